// Round 2
// baseline (37895.435 us; speedup 1.0000x reference)
//
#include <hip/hip_runtime.h>
#include <math.h>

// Problem constants
#define BB 32
#define CC 512
#define SS 256
#define DD 2048
#define DIN 512
#define NH 8
#define DHD 64
#define TT 50
#define MM 25
#define NSA 512
#define NSO 512
#define NOUT 1000
#define NBLK 256

// ---------------------------------------------------------------------------
// Init: decays, double-buffered sync states, act0, trace0, barrier state
// ---------------------------------------------------------------------------
__global__ void init_kernel(const float* __restrict__ dec_a, const float* __restrict__ dec_o,
                            const float* __restrict__ start_act, const float* __restrict__ start_trace,
                            const int* __restrict__ idx_lo, const int* __restrict__ idx_ro,
                            float* __restrict__ r_a, float* __restrict__ r_o,
                            float* __restrict__ aab, float* __restrict__ bab,
                            float* __restrict__ aob, float* __restrict__ bob,
                            float* __restrict__ act, float* __restrict__ trace,
                            unsigned* __restrict__ bar)
{
    int i = blockIdx.x * 256 + threadIdx.x;
    if (i < 2) bar[i] = 0u;
    if (i < 512) {
        r_a[i] = expf(-fminf(fmaxf(dec_a[i], 0.f), 15.f));
        r_o[i] = expf(-fminf(fmaxf(dec_o[i], 0.f), 15.f));
    }
    if (i < BB * NSA) {
        aab[i] = 0.f; bab[i] = 0.f; aab[16384 + i] = 0.f; bab[16384 + i] = 0.f;
        int j = i & 511;
        aob[i] = start_act[idx_lo[j]] * start_act[idx_ro[j]];
        bob[i] = 1.f;
        aob[16384 + i] = 0.f; bob[16384 + i] = 0.f;
    }
    if (i < BB * DD) act[i] = start_act[i & (DD - 1)];
    if (i < BB * MM * DD) {
        int rem = i % (MM * DD);
        int m = rem / DD, d = rem % DD;
        trace[i] = start_trace[d * MM + m];   // start_trace is (D,M); trace layout [b][m][d]
    }
}

// ---------------------------------------------------------------------------
// Precompute GEMMs (verbatim from round 1)
// ---------------------------------------------------------------------------
template<int AMODE, int SMODE>
__global__ void gemm64(const float* __restrict__ A, const float* __restrict__ Bm,
                       const float* __restrict__ bias, float* __restrict__ Cm,
                       int Mdim, int Ndim, int Kdim)
{
    __shared__ float As[16 * 65];
    __shared__ float Bs[16 * 64];
    int row0 = blockIdx.x * 64;
    int col0 = blockIdx.y * 64;
    int t = threadIdx.x;
    int tx = t & 15, ty = t >> 4;
    float acc[4][4] = {};
    for (int k0 = 0; k0 < Kdim; k0 += 16) {
        if (AMODE == 0) {
            for (int i = t; i < 1024; i += 256) {
                int kk = i & 15, r = i >> 4;
                As[kk * 65 + r] = A[(size_t)(row0 + r) * Kdim + k0 + kk];
            }
        } else {
            int b = row0 / SS, s0 = row0 % SS;
            for (int i = t; i < 1024; i += 256) {
                int r = i & 63, kk = i >> 6;
                As[kk * 65 + r] = A[((size_t)b * CC + k0 + kk) * SS + s0 + r];
            }
        }
        for (int i = t; i < 1024; i += 256) {
            int c = i & 63, kk = i >> 6;
            Bs[kk * 64 + c] = Bm[(size_t)(k0 + kk) * Ndim + col0 + c];
        }
        __syncthreads();
        #pragma unroll
        for (int kk = 0; kk < 16; ++kk) {
            float a[4], bb[4];
            #pragma unroll
            for (int i = 0; i < 4; i++) a[i] = As[kk * 65 + ty * 4 + i];
            #pragma unroll
            for (int j = 0; j < 4; j++) bb[j] = Bs[kk * 64 + tx * 4 + j];
            #pragma unroll
            for (int i = 0; i < 4; i++)
                #pragma unroll
                for (int j = 0; j < 4; j++) acc[i][j] += a[i] * bb[j];
        }
        __syncthreads();
    }
    #pragma unroll
    for (int i = 0; i < 4; i++)
        #pragma unroll
        for (int j = 0; j < 4; j++) {
            int row = row0 + ty * 4 + i, col = col0 + tx * 4 + j;
            float v = acc[i][j] + (bias ? bias[col] : 0.f);
            if (SMODE == 0) {
                Cm[(size_t)row * Ndim + col] = v;
            } else if (SMODE == 1) {
                int b = row / SS, s = row % SS, h = col >> 6, dh = col & 63;
                Cm[(((size_t)b * NH + h) * DHD + dh) * SS + s] = v;
            } else {
                int b = row / SS, s = row % SS, h = col >> 6, dh = col & 63;
                Cm[(((size_t)b * NH + h) * SS + s) * DHD + dh] = v;
            }
        }
}

__global__ void ln_rows(float* __restrict__ buf, const float* __restrict__ g,
                        const float* __restrict__ bta)
{
    int row = blockIdx.x, t = threadIdx.x;
    __shared__ float red[256];
    float v0 = buf[(size_t)row * 512 + t];
    float v1 = buf[(size_t)row * 512 + 256 + t];
    red[t] = v0 + v1; __syncthreads();
    for (int off = 128; off; off >>= 1) { if (t < off) red[t] += red[t + off]; __syncthreads(); }
    float mu = red[0] * (1.f / 512.f); __syncthreads();
    float d0 = v0 - mu, d1 = v1 - mu;
    red[t] = d0 * d0 + d1 * d1; __syncthreads();
    for (int off = 128; off; off >>= 1) { if (t < off) red[t] += red[t + off]; __syncthreads(); }
    float rstd = 1.f / sqrtf(red[0] * (1.f / 512.f) + 1e-5f);
    buf[(size_t)row * 512 + t]       = d0 * rstd * g[t] + bta[t];
    buf[(size_t)row * 512 + 256 + t] = d1 * rstd * g[t + 256] + bta[t + 256];
}

__global__ void bqq_kernel(const float* __restrict__ q_b, const float* __restrict__ Wq,
                           const float* __restrict__ bq, float* __restrict__ bqq)
{
    int c = blockIdx.x * 256 + threadIdx.x;
    if (c >= 512) return;
    float acc = bq[c];
    for (int k = 0; k < 512; k++) acc += q_b[k] * Wq[k * 512 + c];
    bqq[c] = acc;
}

__global__ void bias2_kernel(const float* __restrict__ bo, const float* __restrict__ syn_w,
                             const float* __restrict__ syn_b, float* __restrict__ bias2)
{
    int c = blockIdx.x * 256 + threadIdx.x;
    if (c >= 4096) return;
    float acc = syn_b[c];
    for (int k = 0; k < 512; k++) acc += bo[k] * syn_w[(size_t)k * 4096 + c];
    bias2[c] = acc;
}

// ---------------------------------------------------------------------------
// Grid barrier (monotone counter + generation). All 256 blocks co-resident:
// 256 blocks <= 256 CUs, block 256 thr / ~22KB LDS -> capacity >= 1 blk/CU.
// ---------------------------------------------------------------------------
__device__ inline void gbar(unsigned* bar)
{
    __syncthreads();
    if (threadIdx.x == 0) {
        __threadfence();   // release: flush L2 to coherent point
        unsigned arr = __hip_atomic_fetch_add(&bar[0], 1u, __ATOMIC_ACQ_REL, __HIP_MEMORY_SCOPE_AGENT);
        unsigned tgt = arr / (unsigned)NBLK + 1u;
        if ((arr % (unsigned)NBLK) == (unsigned)NBLK - 1u)
            __hip_atomic_fetch_add(&bar[1], 1u, __ATOMIC_ACQ_REL, __HIP_MEMORY_SCOPE_AGENT);
        while (__hip_atomic_load(&bar[1], __ATOMIC_ACQUIRE, __HIP_MEMORY_SCOPE_AGENT) < tgt)
            __builtin_amdgcn_s_sleep(1);
        __threadfence();   // acquire: invalidate stale L1/L2
    }
    __syncthreads();
}

union LDSU {
    struct { float syncA[512]; float qs[64]; float red[256]; float ps[256]; } a;  // P1 unit A
    struct { float so[512]; float red[256]; } b;                                   // P1 unit B
    struct { float As[32 * 161]; float red[256]; } s;                              // P2 syn
    struct { float red[256]; } g;                                                  // P3/cert
};

// ---------------------------------------------------------------------------
// Persistent mega-kernel: all 50 ticks, 4 grid barriers per tick
// ---------------------------------------------------------------------------
__global__ void __launch_bounds__(256)
mega_kernel(const float* __restrict__ Wqq, const float* __restrict__ bqq,
            const float* __restrict__ khT, const float* __restrict__ vh,
            const float* __restrict__ W2, const float* __restrict__ syn_w,
            const float* __restrict__ bias2,
            const float* __restrict__ ln_g, const float* __restrict__ ln_b,
            const float* __restrict__ w1, const float* __restrict__ b1,
            const float* __restrict__ w2, const float* __restrict__ b2,
            const float* __restrict__ out_w, const float* __restrict__ out_b,
            const float* __restrict__ r_a, const float* __restrict__ r_o,
            const int* __restrict__ la, const int* __restrict__ ra,
            const int* __restrict__ lo, const int* __restrict__ ro,
            float* aab, float* bab, float* aob, float* bob,
            float* act, float* trace, float* obuf, float* upart,
            float* predbuf, float* out, float* out_sync, unsigned* bar)
{
    __shared__ LDSU ls;
    const int bid = blockIdx.x;
    const int t = threadIdx.x;
    const int b = bid >> 3, h = bid & 7;   // (b,h) decomposition for P1

    for (int tick = 0; tick <= TT; ++tick) {
        // =============== P1: sync_a + qh + attn  |  sync_o(t-1) + pred(t-1) ===============
        if (tick < TT) {
            const float* actb = act + b * DD;
            {   // sync_a (redundant per h; h==0 writes state; parity double-buffer)
                const int rd = tick & 1, wr = 1 - rd;
                const float* AAr = aab + rd * 16384; float* AAw = aab + wr * 16384;
                const float* BAr = bab + rd * 16384; float* BAw = bab + wr * 16384;
                #pragma unroll
                for (int jj = 0; jj < 2; ++jj) {
                    int j = t + jj * 256;
                    float p = actb[la[j]] * actb[ra[j]];
                    float aa = r_a[j] * AAr[b * 512 + j] + p;
                    float bb2 = r_a[j] * BAr[b * 512 + j] + 1.f;
                    if (h == 0) { AAw[b * 512 + j] = aa; BAw[b * 512 + j] = bb2; }
                    ls.a.syncA[j] = aa / sqrtf(bb2);
                }
            }
            __syncthreads();
            {   // qh for head h: 64 cols, k split over 4 thread groups
                int cl = t & 63, kq = t >> 6;
                const float* wp = Wqq + (size_t)(kq * 128) * 512 + h * 64 + cl;
                const float* sp = ls.a.syncA + kq * 128;
                float part = 0.f;
                #pragma unroll 8
                for (int k = 0; k < 128; ++k) part += sp[k] * wp[(size_t)k * 512];
                ls.a.red[t] = part;
            }
            __syncthreads();
            if (t < 64)
                ls.a.qs[t] = ls.a.red[t] + ls.a.red[t + 64] + ls.a.red[t + 128] + ls.a.red[t + 192]
                           + bqq[h * 64 + t];
            __syncthreads();
            {   // attention for (b,h)
                const float* kb = khT + (size_t)bid * 64 * 256;   // [dh][s]
                float sc = 0.f;
                #pragma unroll 8
                for (int dh = 0; dh < 64; ++dh) sc += ls.a.qs[dh] * kb[dh * 256 + t];
                sc *= 0.125f;
                ls.a.red[t] = sc; __syncthreads();
                for (int off = 128; off; off >>= 1) { if (t < off) ls.a.red[t] = fmaxf(ls.a.red[t], ls.a.red[t + off]); __syncthreads(); }
                float mx = ls.a.red[0]; __syncthreads();
                float e = expf(sc - mx);
                ls.a.red[t] = e; __syncthreads();
                for (int off = 128; off; off >>= 1) { if (t < off) ls.a.red[t] += ls.a.red[t + off]; __syncthreads(); }
                float inv = 1.f / ls.a.red[0];
                ls.a.ps[t] = e * inv;
                __syncthreads();
                int dh = t & 63, ch = t >> 6;
                const float* vb = vh + (size_t)bid * 256 * 64;    // [s][dh]
                float acc2 = 0.f;
                for (int s2 = ch * 64; s2 < ch * 64 + 64; ++s2) acc2 += ls.a.ps[s2] * vb[s2 * 64 + dh];
                ls.a.red[t] = acc2; __syncthreads();
                if (t < 128) ls.a.red[t] += ls.a.red[t + 128];
                __syncthreads();
                if (t < 64) obuf[b * 512 + h * 64 + t] = ls.a.red[t] + ls.a.red[t + 64];
            }
        }
        if (tick > 0) {   // unit B: sync_o(s) + pred(s), s = tick-1; ctile = h
            __syncthreads();
            const int s = tick - 1;
            const int rd = s & 1, wr = 1 - rd;
            const float* actb = act + b * DD;
            const float* AOr = aob + rd * 16384; float* AOw = aob + wr * 16384;
            const float* BOr = bob + rd * 16384; float* BOw = bob + wr * 16384;
            #pragma unroll
            for (int jj = 0; jj < 2; ++jj) {
                int j = t + jj * 256;
                float p = actb[lo[j]] * actb[ro[j]];
                float aa = r_o[j] * AOr[b * 512 + j] + p;
                float bb2 = r_o[j] * BOr[b * 512 + j] + 1.f;
                if (h == 0) { AOw[b * 512 + j] = aa; BOw[b * 512 + j] = bb2; }
                float sv = aa / sqrtf(bb2);
                ls.b.so[j] = sv;
                if (s == TT - 1 && h == 0) out_sync[b * 512 + j] = sv;
            }
            __syncthreads();
            {   // pred: 125 cols for this (b,ctile), K split in halves of 256
                int cl = t & 127, kh2 = t >> 7;
                float part = 0.f;
                if (cl < 125) {
                    int c = h * 125 + cl;
                    const float* wp = out_w + (size_t)(kh2 * 256) * 1000 + c;
                    const float* sp = ls.b.so + kh2 * 256;
                    #pragma unroll 8
                    for (int k = 0; k < 256; ++k) part += sp[k] * wp[(size_t)k * 1000];
                }
                ls.b.red[t] = part;
            }
            __syncthreads();
            if (t < 125) {
                int c = h * 125 + t;
                float v = ls.b.red[t] + ls.b.red[t + 128] + out_b[c];
                predbuf[b * 1000 + c] = v;
                out[(size_t)b * NOUT * TT + (size_t)c * TT + s] = v;
            }
        }
        gbar(bar);

        // =============== P2: syn GEMM (512 units / 256 blocks) + cert(t-1) ===============
        if (tick < TT) {
            for (int u = bid; u < 512; u += 256) {
                int n0 = (u & 31) * 128;
                int ks = u >> 5;
                int k0 = ks * 160;
                for (int i = t; i < 32 * 160; i += 256) {
                    int k = i % 160, r = i / 160;
                    int kk = k0 + k;
                    ls.s.As[r * 161 + k] = (kk < 512) ? obuf[r * 512 + kk] : act[r * 2048 + (kk - 512)];
                }
                __syncthreads();
                int ct = t & 31, rt = t >> 5;
                int c0 = n0 + ct * 4, rt4 = rt * 4;
                float acc[4][4] = {};
                #pragma unroll 2
                for (int k = 0; k < 160; ++k) {
                    int kk = k0 + k;
                    const float* wr2 = (kk < 512 ? W2 : syn_w) + (size_t)kk * 4096 + c0;
                    float4 w4 = *(const float4*)wr2;
                    float a0 = ls.s.As[(rt4 + 0) * 161 + k];
                    float a1 = ls.s.As[(rt4 + 1) * 161 + k];
                    float a2 = ls.s.As[(rt4 + 2) * 161 + k];
                    float a3 = ls.s.As[(rt4 + 3) * 161 + k];
                    acc[0][0] += a0 * w4.x; acc[0][1] += a0 * w4.y; acc[0][2] += a0 * w4.z; acc[0][3] += a0 * w4.w;
                    acc[1][0] += a1 * w4.x; acc[1][1] += a1 * w4.y; acc[1][2] += a1 * w4.z; acc[1][3] += a1 * w4.w;
                    acc[2][0] += a2 * w4.x; acc[2][1] += a2 * w4.y; acc[2][2] += a2 * w4.z; acc[2][3] += a2 * w4.w;
                    acc[3][0] += a3 * w4.x; acc[3][1] += a3 * w4.y; acc[3][2] += a3 * w4.z; acc[3][3] += a3 * w4.w;
                }
                #pragma unroll
                for (int i = 0; i < 4; i++) {
                    float4 v = make_float4(acc[i][0], acc[i][1], acc[i][2], acc[i][3]);
                    *(float4*)(upart + ((size_t)(ks * 32) + rt4 + i) * 4096 + c0) = v;
                }
                __syncthreads();
            }
        }
        if (tick > 0 && bid >= 224) {   // cert(s), s = tick-1, b2 = bid-224
            const int s = tick - 1;
            const int b2 = bid - 224;
            float pv[4];
            float mx = -1e30f;
            #pragma unroll
            for (int ii = 0; ii < 4; ++ii) {
                int c = t + ii * 256;
                float v = (c < 1000) ? predbuf[b2 * 1000 + c] : -1e30f;
                pv[ii] = v;
                mx = fmaxf(mx, v);
            }
            ls.g.red[t] = mx; __syncthreads();
            for (int off = 128; off; off >>= 1) { if (t < off) ls.g.red[t] = fmaxf(ls.g.red[t], ls.g.red[t + off]); __syncthreads(); }
            mx = ls.g.red[0]; __syncthreads();
            float s1 = 0.f, s2 = 0.f;
            #pragma unroll
            for (int ii = 0; ii < 4; ++ii) {
                int c = t + ii * 256;
                if (c < 1000) { float xx = pv[ii] - mx; float e = expf(xx); s1 += e; s2 += e * xx; }
            }
            ls.g.red[t] = s1; __syncthreads();
            for (int off = 128; off; off >>= 1) { if (t < off) ls.g.red[t] += ls.g.red[t + off]; __syncthreads(); }
            s1 = ls.g.red[0]; __syncthreads();
            ls.g.red[t] = s2; __syncthreads();
            for (int off = 128; off; off >>= 1) { if (t < off) ls.g.red[t] += ls.g.red[t + off]; __syncthreads(); }
            s2 = ls.g.red[0];
            if (t == 0) {
                float ne = -(s2 / s1 - logf(s1)) * (1.f / logf(1000.f));
                size_t base = (size_t)BB * NOUT * TT + (size_t)b2 * 2 * TT + s;
                out[base] = ne;
                out[base + TT] = 1.f - ne;
            }
        }
        gbar(bar);

        // =============== P3: glu_ln (32 blocks active) ===============
        if (tick < TT && bid < 32) {
            const int gb = bid;
            float vals[8];
            float loc = 0.f;
            #pragma unroll
            for (int ii = 0; ii < 8; ++ii) {
                int d = t + ii * 256;
                float a = bias2[d], bb2 = bias2[d + 2048];
                for (int ks = 0; ks < 16; ++ks) {
                    const float* rowp = upart + (size_t)(ks * 32 + gb) * 4096;
                    a += rowp[d];
                    bb2 += rowp[d + 2048];
                }
                float gl = a * (1.f / (1.f + expf(-bb2)));
                vals[ii] = gl; loc += gl;
            }
            ls.g.red[t] = loc; __syncthreads();
            for (int off = 128; off; off >>= 1) { if (t < off) ls.g.red[t] += ls.g.red[t + off]; __syncthreads(); }
            float mu = ls.g.red[0] * (1.f / 2048.f); __syncthreads();
            float l2 = 0.f;
            #pragma unroll
            for (int ii = 0; ii < 8; ++ii) { float dq = vals[ii] - mu; l2 += dq * dq; }
            ls.g.red[t] = l2; __syncthreads();
            for (int off = 128; off; off >>= 1) { if (t < off) ls.g.red[t] += ls.g.red[t + off]; __syncthreads(); }
            float rstd = 1.f / sqrtf(ls.g.red[0] * (1.f / 2048.f) + 1e-5f);
            float* trow = trace + ((size_t)gb * MM + (tick % MM)) * DD;
            #pragma unroll
            for (int ii = 0; ii < 8; ++ii) {
                int d = t + ii * 256;
                trow[d] = (vals[ii] - mu) * rstd * ln_g[d] + ln_b[d];
            }
        }
        gbar(bar);

        // =============== P4: nlm (thread per (b,d)) ===============
        if (tick < TT) {
            int i = bid * 256 + t;
            int b4 = i >> 11, d = i & 2047;
            float hp[32];
            #pragma unroll
            for (int hh = 0; hh < 32; hh++) hp[hh] = b1[d * 32 + hh];
            const float* tr = trace + (size_t)b4 * MM * DD;
            for (int m = 0; m < 25; m++) {
                int mph = (tick + 1 + m) % 25;
                float tv = tr[mph * DD + d];
                #pragma unroll
                for (int hh = 0; hh < 32; hh++) hp[hh] += tv * w1[((size_t)m * 32 + hh) * DD + d];
            }
            float o0 = b2[d * 2], o1 = b2[d * 2 + 1];
            #pragma unroll
            for (int hh = 0; hh < 16; hh++) {
                float hv = hp[hh] * (1.f / (1.f + expf(-hp[hh + 16])));
                o0 += hv * w2[((size_t)hh * 2) * DD + d];
                o1 += hv * w2[((size_t)hh * 2 + 1) * DD + d];
            }
            act[i] = o0 * (1.f / (1.f + expf(-o1)));
        }
        gbar(bar);
    }
}

// ---------------------------------------------------------------------------
extern "C" void kernel_launch(void* const* d_in, const int* in_sizes, int n_in,
                              void* d_out, int out_size, void* d_ws, size_t ws_size,
                              hipStream_t stream)
{
    const float* x        = (const float*)d_in[0];
    const float* kv_w     = (const float*)d_in[1];
    const float* kv_b     = (const float*)d_in[2];
    const float* ln_kv_g  = (const float*)d_in[3];
    const float* ln_kv_b  = (const float*)d_in[4];
    const float* q_w      = (const float*)d_in[5];
    const float* q_b      = (const float*)d_in[6];
    const float* Wq       = (const float*)d_in[7];
    const float* bq       = (const float*)d_in[8];
    const float* Wk       = (const float*)d_in[9];
    const float* bk       = (const float*)d_in[10];
    const float* Wv       = (const float*)d_in[11];
    const float* bv       = (const float*)d_in[12];
    const float* Wo       = (const float*)d_in[13];
    const float* bo       = (const float*)d_in[14];
    const float* syn_w    = (const float*)d_in[15];
    const float* syn_b    = (const float*)d_in[16];
    const float* ln_syn_g = (const float*)d_in[17];
    const float* ln_syn_b = (const float*)d_in[18];
    const float* nlm_w1   = (const float*)d_in[19];
    const float* nlm_b1   = (const float*)d_in[20];
    const float* nlm_w2   = (const float*)d_in[21];
    const float* nlm_b2   = (const float*)d_in[22];
    const float* out_w    = (const float*)d_in[23];
    const float* out_b    = (const float*)d_in[24];
    const float* dec_a    = (const float*)d_in[25];
    const float* dec_o    = (const float*)d_in[26];
    const float* start_tr = (const float*)d_in[27];
    const float* start_ac = (const float*)d_in[28];
    const int*   idx_la   = (const int*)d_in[29];
    const int*   idx_ra   = (const int*)d_in[30];
    const int*   idx_lo   = (const int*)d_in[31];
    const int*   idx_ro   = (const int*)d_in[32];
    float* out = (float*)d_out;

    // workspace carve (floats)
    float* w = (float*)d_ws;
    float* kvbuf = w;            w += (size_t)8192 * 512;
    float* khT   = w;            w += (size_t)8192 * 512;
    float* vhb   = w;            w += (size_t)8192 * 512;
    float* Wqq   = w;            w += (size_t)512 * 512;
    float* bqq   = w;            w += 512;
    float* W2    = w;            w += (size_t)512 * 4096;
    float* bias2 = w;            w += 4096;
    float* r_a   = w;            w += 512;
    float* r_o   = w;            w += 512;
    float* aab   = w;            w += 2 * BB * NSA;
    float* bab   = w;            w += 2 * BB * NSA;
    float* aob   = w;            w += 2 * BB * NSO;
    float* bob   = w;            w += 2 * BB * NSO;
    float* act   = w;            w += BB * DD;
    float* trace = w;            w += (size_t)BB * MM * DD;
    float* obuf  = w;            w += BB * DIN;
    float* upart = w;            w += (size_t)16 * 32 * 4096;
    float* predbuf = w;          w += BB * NOUT;
    unsigned* bar = (unsigned*)w; w += 16;

    // ---- precompute ----
    init_kernel<<<6400, 256, 0, stream>>>(dec_a, dec_o, start_ac, start_tr, idx_lo, idx_ro,
                                          r_a, r_o, aab, bab, aob, bob, act, trace, bar);
    gemm64<1, 0><<<dim3(128, 8), 256, 0, stream>>>(x, kv_w, kv_b, kvbuf, 8192, 512, 512);
    ln_rows<<<8192, 256, 0, stream>>>(kvbuf, ln_kv_g, ln_kv_b);
    gemm64<0, 1><<<dim3(128, 8), 256, 0, stream>>>(kvbuf, Wk, bk, khT, 8192, 512, 512);
    gemm64<0, 2><<<dim3(128, 8), 256, 0, stream>>>(kvbuf, Wv, bv, vhb, 8192, 512, 512);
    gemm64<0, 0><<<dim3(8, 8), 256, 0, stream>>>(q_w, Wq, nullptr, Wqq, 512, 512, 512);
    bqq_kernel<<<2, 256, 0, stream>>>(q_b, Wq, bq, bqq);
    gemm64<0, 0><<<dim3(8, 64), 256, 0, stream>>>(Wo, syn_w, nullptr, W2, 512, 4096, 512);
    bias2_kernel<<<16, 256, 0, stream>>>(bo, syn_w, syn_b, bias2);

    float* out_sync = out + (size_t)BB * NOUT * TT + (size_t)BB * 2 * TT;

    // ---- persistent 50-tick loop ----
    mega_kernel<<<NBLK, 256, 0, stream>>>(Wqq, bqq, khT, vhb, W2, syn_w, bias2,
                                          ln_syn_g, ln_syn_b,
                                          nlm_w1, nlm_b1, nlm_w2, nlm_b2,
                                          out_w, out_b, r_a, r_o,
                                          idx_la, idx_ra, idx_lo, idx_ro,
                                          aab, bab, aob, bob,
                                          act, trace, obuf, upart,
                                          predbuf, out, out_sync, bar);
}

// Round 3
// 20834.985 us; speedup vs baseline: 1.8188x; 1.8188x over previous
//
#include <hip/hip_runtime.h>
#include <math.h>

// Problem constants
#define BB 32
#define CC 512
#define SS 256
#define DD 2048
#define DIN 512
#define NH 8
#define DHD 64
#define TT 50
#define MM 25
#define NSA 512
#define NSO 512
#define NOUT 1000
#define NBLK 512

// ---------------------------------------------------------------------------
// Coherent-point (cross-XCD) data movement WITHOUT fences: relaxed agent-scope
// atomics bypass the non-coherent per-XCD L2s. Weights stay normal (cached).
// ---------------------------------------------------------------------------
__device__ __forceinline__ float aload(const float* p) {
    return __hip_atomic_load(const_cast<float*>(p), __ATOMIC_RELAXED, __HIP_MEMORY_SCOPE_AGENT);
}
__device__ __forceinline__ void astore(float* p, float v) {
    __hip_atomic_store(p, v, __ATOMIC_RELAXED, __HIP_MEMORY_SCOPE_AGENT);
}
__device__ __forceinline__ void astore2(float* p, float a, float b) {
    union { float f[2]; unsigned long long u; } x; x.f[0] = a; x.f[1] = b;
    __hip_atomic_store((unsigned long long*)p, x.u, __ATOMIC_RELAXED, __HIP_MEMORY_SCOPE_AGENT);
}

// ---------------------------------------------------------------------------
// Init: decays, double-buffered sync states, act0, trace0, barrier state
// ---------------------------------------------------------------------------
__global__ void init_kernel(const float* __restrict__ dec_a, const float* __restrict__ dec_o,
                            const float* __restrict__ start_act, const float* __restrict__ start_trace,
                            const int* __restrict__ idx_lo, const int* __restrict__ idx_ro,
                            float* __restrict__ r_a, float* __restrict__ r_o,
                            float* __restrict__ aab, float* __restrict__ bab,
                            float* __restrict__ aob, float* __restrict__ bob,
                            float* __restrict__ act, float* __restrict__ trace,
                            unsigned* __restrict__ bar)
{
    int i = blockIdx.x * 256 + threadIdx.x;
    if (i < 2) bar[i] = 0u;
    if (i < 512) {
        r_a[i] = expf(-fminf(fmaxf(dec_a[i], 0.f), 15.f));
        r_o[i] = expf(-fminf(fmaxf(dec_o[i], 0.f), 15.f));
    }
    if (i < BB * NSA) {
        aab[i] = 0.f; bab[i] = 0.f; aab[16384 + i] = 0.f; bab[16384 + i] = 0.f;
        int j = i & 511;
        aob[i] = start_act[idx_lo[j]] * start_act[idx_ro[j]];
        bob[i] = 1.f;
        aob[16384 + i] = 0.f; bob[16384 + i] = 0.f;
    }
    if (i < BB * DD) act[i] = start_act[i & (DD - 1)];
    if (i < BB * MM * DD) {
        int rem = i % (MM * DD);
        int m = rem / DD, d = rem % DD;
        trace[i] = start_trace[d * MM + m];   // start_trace is (D,M); trace layout [b][m][d]
    }
}

// ---------------------------------------------------------------------------
// Precompute GEMMs (verbatim, validated round 1)
// ---------------------------------------------------------------------------
template<int AMODE, int SMODE>
__global__ void gemm64(const float* __restrict__ A, const float* __restrict__ Bm,
                       const float* __restrict__ bias, float* __restrict__ Cm,
                       int Mdim, int Ndim, int Kdim)
{
    __shared__ float As[16 * 65];
    __shared__ float Bs[16 * 64];
    int row0 = blockIdx.x * 64;
    int col0 = blockIdx.y * 64;
    int t = threadIdx.x;
    int tx = t & 15, ty = t >> 4;
    float acc[4][4] = {};
    for (int k0 = 0; k0 < Kdim; k0 += 16) {
        if (AMODE == 0) {
            for (int i = t; i < 1024; i += 256) {
                int kk = i & 15, r = i >> 4;
                As[kk * 65 + r] = A[(size_t)(row0 + r) * Kdim + k0 + kk];
            }
        } else {
            int b = row0 / SS, s0 = row0 % SS;
            for (int i = t; i < 1024; i += 256) {
                int r = i & 63, kk = i >> 6;
                As[kk * 65 + r] = A[((size_t)b * CC + k0 + kk) * SS + s0 + r];
            }
        }
        for (int i = t; i < 1024; i += 256) {
            int c = i & 63, kk = i >> 6;
            Bs[kk * 64 + c] = Bm[(size_t)(k0 + kk) * Ndim + col0 + c];
        }
        __syncthreads();
        #pragma unroll
        for (int kk = 0; kk < 16; ++kk) {
            float a[4], bb[4];
            #pragma unroll
            for (int i = 0; i < 4; i++) a[i] = As[kk * 65 + ty * 4 + i];
            #pragma unroll
            for (int j = 0; j < 4; j++) bb[j] = Bs[kk * 64 + tx * 4 + j];
            #pragma unroll
            for (int i = 0; i < 4; i++)
                #pragma unroll
                for (int j = 0; j < 4; j++) acc[i][j] += a[i] * bb[j];
        }
        __syncthreads();
    }
    #pragma unroll
    for (int i = 0; i < 4; i++)
        #pragma unroll
        for (int j = 0; j < 4; j++) {
            int row = row0 + ty * 4 + i, col = col0 + tx * 4 + j;
            float v = acc[i][j] + (bias ? bias[col] : 0.f);
            if (SMODE == 0) {
                Cm[(size_t)row * Ndim + col] = v;
            } else if (SMODE == 1) {
                int b = row / SS, s = row % SS, h = col >> 6, dh = col & 63;
                Cm[(((size_t)b * NH + h) * DHD + dh) * SS + s] = v;
            } else {
                int b = row / SS, s = row % SS, h = col >> 6, dh = col & 63;
                Cm[(((size_t)b * NH + h) * SS + s) * DHD + dh] = v;
            }
        }
}

__global__ void ln_rows(float* __restrict__ buf, const float* __restrict__ g,
                        const float* __restrict__ bta)
{
    int row = blockIdx.x, t = threadIdx.x;
    __shared__ float red[256];
    float v0 = buf[(size_t)row * 512 + t];
    float v1 = buf[(size_t)row * 512 + 256 + t];
    red[t] = v0 + v1; __syncthreads();
    for (int off = 128; off; off >>= 1) { if (t < off) red[t] += red[t + off]; __syncthreads(); }
    float mu = red[0] * (1.f / 512.f); __syncthreads();
    float d0 = v0 - mu, d1 = v1 - mu;
    red[t] = d0 * d0 + d1 * d1; __syncthreads();
    for (int off = 128; off; off >>= 1) { if (t < off) red[t] += red[t + off]; __syncthreads(); }
    float rstd = 1.f / sqrtf(red[0] * (1.f / 512.f) + 1e-5f);
    buf[(size_t)row * 512 + t]       = d0 * rstd * g[t] + bta[t];
    buf[(size_t)row * 512 + 256 + t] = d1 * rstd * g[t + 256] + bta[t + 256];
}

__global__ void bqq_kernel(const float* __restrict__ q_b, const float* __restrict__ Wq,
                           const float* __restrict__ bq, float* __restrict__ bqq)
{
    int c = blockIdx.x * 256 + threadIdx.x;
    if (c >= 512) return;
    float acc = bq[c];
    for (int k = 0; k < 512; k++) acc += q_b[k] * Wq[k * 512 + c];
    bqq[c] = acc;
}

__global__ void bias2_kernel(const float* __restrict__ bo, const float* __restrict__ syn_w,
                             const float* __restrict__ syn_b, float* __restrict__ bias2)
{
    int c = blockIdx.x * 256 + threadIdx.x;
    if (c >= 4096) return;
    float acc = syn_b[c];
    for (int k = 0; k < 512; k++) acc += bo[k] * syn_w[(size_t)k * 4096 + c];
    bias2[c] = acc;
}

// ---------------------------------------------------------------------------
// Fence-free grid barrier. Ordering: each wave drains vmcnt(0) (all agent-
// scope stores acked at coherent point), syncthreads, then relaxed arrive.
// A reader observing the new generation therefore observes the data.
// 512 blocks, 2 blocks/CU guaranteed resident (VGPR<=256, LDS 22KB).
// ---------------------------------------------------------------------------
__device__ __forceinline__ void gbar(unsigned* bar)
{
    asm volatile("s_waitcnt vmcnt(0)" ::: "memory");
    __syncthreads();
    if (threadIdx.x == 0) {
        unsigned arr = __hip_atomic_fetch_add(&bar[0], 1u, __ATOMIC_RELAXED, __HIP_MEMORY_SCOPE_AGENT);
        unsigned tgt = arr / (unsigned)NBLK + 1u;
        if ((arr % (unsigned)NBLK) == (unsigned)NBLK - 1u)
            __hip_atomic_store(&bar[1], tgt, __ATOMIC_RELAXED, __HIP_MEMORY_SCOPE_AGENT);
        while (__hip_atomic_load(&bar[1], __ATOMIC_RELAXED, __HIP_MEMORY_SCOPE_AGENT) < tgt)
            __builtin_amdgcn_s_sleep(2);
    }
    __syncthreads();
}

union LDSU {
    struct { float syncA[512]; float qs[64]; float red[256]; float ps[256]; } a;  // P1 A
    struct { float so[512]; float red[256]; } b;                                   // P1 B
    struct { float As[32 * 161]; float red[256]; } s;                              // P2 syn
    struct { float red[256]; } g;                                                  // P3/cert
};

// ---------------------------------------------------------------------------
// Persistent mega-kernel: all 50 ticks, 4 fence-free barriers per tick
// ---------------------------------------------------------------------------
__global__ void __launch_bounds__(256, 2)
mega_kernel(const float* __restrict__ Wqq, const float* __restrict__ bqq,
            const float* __restrict__ khT, const float* __restrict__ vh,
            const float* __restrict__ W2, const float* __restrict__ syn_w,
            const float* __restrict__ bias2,
            const float* __restrict__ ln_g, const float* __restrict__ ln_b,
            const float* __restrict__ w1, const float* __restrict__ b1,
            const float* __restrict__ w2, const float* __restrict__ b2,
            const float* __restrict__ out_w, const float* __restrict__ out_b,
            const float* __restrict__ r_a, const float* __restrict__ r_o,
            const int* __restrict__ la, const int* __restrict__ ra,
            const int* __restrict__ lo, const int* __restrict__ ro,
            float* aab, float* bab, float* aob, float* bob,
            float* act, float* trace, float* obuf, float* upart,
            float* predbuf, float* out, float* out_sync, unsigned* bar)
{
    __shared__ LDSU ls;
    const int bid = blockIdx.x;
    const int t = threadIdx.x;
    const int b = (bid & 255) >> 3, h = bid & 7;

    for (int tick = 0; tick <= TT; ++tick) {
        // ========== P1: A-blocks (bid<256): sync_a+qh+attn | B-blocks: sync_o(t-1)+pred ==========
        if (bid < 256 && tick < TT) {
            const float* actb = act + b * DD;
            {   // sync_a (redundant per h; h==0 writes state; parity double-buffer)
                const int rd = tick & 1, wr = 1 - rd;
                const float* AAr = aab + rd * 16384; float* AAw = aab + wr * 16384;
                const float* BAr = bab + rd * 16384; float* BAw = bab + wr * 16384;
                #pragma unroll
                for (int jj = 0; jj < 2; ++jj) {
                    int j = t + jj * 256;
                    float p = aload(&actb[la[j]]) * aload(&actb[ra[j]]);
                    float aa = r_a[j] * aload(&AAr[b * 512 + j]) + p;
                    float bb2 = r_a[j] * aload(&BAr[b * 512 + j]) + 1.f;
                    if (h == 0) { astore(&AAw[b * 512 + j], aa); astore(&BAw[b * 512 + j], bb2); }
                    ls.a.syncA[j] = aa / sqrtf(bb2);
                }
            }
            __syncthreads();
            {   // qh for head h: 64 cols, k split over 4 thread groups
                int cl = t & 63, kq = t >> 6;
                const float* wp = Wqq + (size_t)(kq * 128) * 512 + h * 64 + cl;
                const float* sp = ls.a.syncA + kq * 128;
                float part = 0.f;
                #pragma unroll 8
                for (int k = 0; k < 128; ++k) part += sp[k] * wp[(size_t)k * 512];
                ls.a.red[t] = part;
            }
            __syncthreads();
            if (t < 64)
                ls.a.qs[t] = ls.a.red[t] + ls.a.red[t + 64] + ls.a.red[t + 128] + ls.a.red[t + 192]
                           + bqq[h * 64 + t];
            __syncthreads();
            {   // attention for (b,h)
                const float* kb = khT + (size_t)bid * 64 * 256;   // [dh][s]
                float sc = 0.f;
                #pragma unroll 8
                for (int dh = 0; dh < 64; ++dh) sc += ls.a.qs[dh] * kb[dh * 256 + t];
                sc *= 0.125f;
                ls.a.red[t] = sc; __syncthreads();
                for (int off = 128; off; off >>= 1) { if (t < off) ls.a.red[t] = fmaxf(ls.a.red[t], ls.a.red[t + off]); __syncthreads(); }
                float mx = ls.a.red[0]; __syncthreads();
                float e = expf(sc - mx);
                ls.a.red[t] = e; __syncthreads();
                for (int off = 128; off; off >>= 1) { if (t < off) ls.a.red[t] += ls.a.red[t + off]; __syncthreads(); }
                float inv = 1.f / ls.a.red[0];
                ls.a.ps[t] = e * inv;
                __syncthreads();
                int dh = t & 63, ch = t >> 6;
                const float* vb = vh + (size_t)bid * 256 * 64;    // [s][dh]
                float acc2 = 0.f;
                for (int s2 = ch * 64; s2 < ch * 64 + 64; ++s2) acc2 += ls.a.ps[s2] * vb[s2 * 64 + dh];
                ls.a.red[t] = acc2; __syncthreads();
                if (t < 128) ls.a.red[t] += ls.a.red[t + 128];
                __syncthreads();
                if (t < 64) astore(&obuf[b * 512 + h * 64 + t], ls.a.red[t] + ls.a.red[t + 64]);
            }
        }
        if (bid >= 256 && tick > 0) {   // B: sync_o(s) + pred(s), s = tick-1; ctile = h
            const int s = tick - 1;
            const int rd = s & 1, wr = 1 - rd;
            const float* actb = act + b * DD;
            const float* AOr = aob + rd * 16384; float* AOw = aob + wr * 16384;
            const float* BOr = bob + rd * 16384; float* BOw = bob + wr * 16384;
            #pragma unroll
            for (int jj = 0; jj < 2; ++jj) {
                int j = t + jj * 256;
                float p = aload(&actb[lo[j]]) * aload(&actb[ro[j]]);
                float aa = r_o[j] * aload(&AOr[b * 512 + j]) + p;
                float bb2 = r_o[j] * aload(&BOr[b * 512 + j]) + 1.f;
                if (h == 0) { astore(&AOw[b * 512 + j], aa); astore(&BOw[b * 512 + j], bb2); }
                float sv = aa / sqrtf(bb2);
                ls.b.so[j] = sv;
                if (s == TT - 1 && h == 0) out_sync[b * 512 + j] = sv;
            }
            __syncthreads();
            {   // pred: 125 cols for this (b,ctile), K split in halves of 256
                int cl = t & 127, kh2 = t >> 7;
                float part = 0.f;
                if (cl < 125) {
                    int c = h * 125 + cl;
                    const float* wp = out_w + (size_t)(kh2 * 256) * 1000 + c;
                    const float* sp = ls.b.so + kh2 * 256;
                    #pragma unroll 8
                    for (int k = 0; k < 256; ++k) part += sp[k] * wp[(size_t)k * 1000];
                }
                ls.b.red[t] = part;
            }
            __syncthreads();
            if (t < 125) {
                int c = h * 125 + t;
                float v = ls.b.red[t] + ls.b.red[t + 128] + out_b[c];
                astore(&predbuf[b * 1000 + c], v);
                out[(size_t)b * NOUT * TT + (size_t)c * TT + s] = v;
            }
        }
        gbar(bar);

        // ========== P2: syn GEMM (512 units = 512 blocks) + cert(t-1) on bid<32 ==========
        if (tick < TT) {
            const int u = bid;
            int n0 = (u & 31) * 128;
            int ks = u >> 5;
            int k0 = ks * 160;
            for (int i = t; i < 32 * 160; i += 256) {
                int k = i % 160, r = i / 160;
                int kk = k0 + k;
                ls.s.As[r * 161 + k] = (kk < 512) ? aload(&obuf[r * 512 + kk])
                                                  : aload(&act[r * 2048 + (kk - 512)]);
            }
            __syncthreads();
            int ct = t & 31, rt = t >> 5;
            int c0 = n0 + ct * 4, rt4 = rt * 4;
            float acc[4][4] = {};
            #pragma unroll 2
            for (int k = 0; k < 160; ++k) {
                int kk = k0 + k;
                const float* wr2 = (kk < 512 ? W2 : syn_w) + (size_t)kk * 4096 + c0;
                float4 w4 = *(const float4*)wr2;
                float a0 = ls.s.As[(rt4 + 0) * 161 + k];
                float a1 = ls.s.As[(rt4 + 1) * 161 + k];
                float a2 = ls.s.As[(rt4 + 2) * 161 + k];
                float a3 = ls.s.As[(rt4 + 3) * 161 + k];
                acc[0][0] += a0 * w4.x; acc[0][1] += a0 * w4.y; acc[0][2] += a0 * w4.z; acc[0][3] += a0 * w4.w;
                acc[1][0] += a1 * w4.x; acc[1][1] += a1 * w4.y; acc[1][2] += a1 * w4.z; acc[1][3] += a1 * w4.w;
                acc[2][0] += a2 * w4.x; acc[2][1] += a2 * w4.y; acc[2][2] += a2 * w4.z; acc[2][3] += a2 * w4.w;
                acc[3][0] += a3 * w4.x; acc[3][1] += a3 * w4.y; acc[3][2] += a3 * w4.z; acc[3][3] += a3 * w4.w;
            }
            #pragma unroll
            for (int i = 0; i < 4; i++) {
                float* dst = upart + ((size_t)(ks * 32) + rt4 + i) * 4096 + c0;
                astore2(dst, acc[i][0], acc[i][1]);
                astore2(dst + 2, acc[i][2], acc[i][3]);
            }
            __syncthreads();
        }
        if (tick > 0 && bid < 32) {   // cert(s), s = tick-1, batch = bid
            const int s = tick - 1;
            const int b2 = bid;
            float pv[4];
            float mx = -1e30f;
            #pragma unroll
            for (int ii = 0; ii < 4; ++ii) {
                int c = t + ii * 256;
                float v = (c < 1000) ? aload(&predbuf[b2 * 1000 + c]) : -1e30f;
                pv[ii] = v;
                mx = fmaxf(mx, v);
            }
            ls.g.red[t] = mx; __syncthreads();
            for (int off = 128; off; off >>= 1) { if (t < off) ls.g.red[t] = fmaxf(ls.g.red[t], ls.g.red[t + off]); __syncthreads(); }
            mx = ls.g.red[0]; __syncthreads();
            float s1 = 0.f, s2 = 0.f;
            #pragma unroll
            for (int ii = 0; ii < 4; ++ii) {
                int c = t + ii * 256;
                if (c < 1000) { float xx = pv[ii] - mx; float e = expf(xx); s1 += e; s2 += e * xx; }
            }
            ls.g.red[t] = s1; __syncthreads();
            for (int off = 128; off; off >>= 1) { if (t < off) ls.g.red[t] += ls.g.red[t + off]; __syncthreads(); }
            s1 = ls.g.red[0]; __syncthreads();
            ls.g.red[t] = s2; __syncthreads();
            for (int off = 128; off; off >>= 1) { if (t < off) ls.g.red[t] += ls.g.red[t + off]; __syncthreads(); }
            s2 = ls.g.red[0];
            if (t == 0) {
                float ne = -(s2 / s1 - logf(s1)) * (1.f / logf(1000.f));
                size_t base = (size_t)BB * NOUT * TT + (size_t)b2 * 2 * TT + s;
                out[base] = ne;
                out[base + TT] = 1.f - ne;
            }
        }
        gbar(bar);

        // ========== P3: glu_ln (32 blocks active) ==========
        if (tick < TT && bid < 32) {
            const int gb = bid;
            float vals[8];
            float loc = 0.f;
            #pragma unroll
            for (int ii = 0; ii < 8; ++ii) {
                int d = t + ii * 256;
                float a = bias2[d], bb2 = bias2[d + 2048];
                for (int ks = 0; ks < 16; ++ks) {
                    const float* rowp = upart + (size_t)(ks * 32 + gb) * 4096;
                    a += aload(&rowp[d]);
                    bb2 += aload(&rowp[d + 2048]);
                }
                float gl = a * (1.f / (1.f + expf(-bb2)));
                vals[ii] = gl; loc += gl;
            }
            ls.g.red[t] = loc; __syncthreads();
            for (int off = 128; off; off >>= 1) { if (t < off) ls.g.red[t] += ls.g.red[t + off]; __syncthreads(); }
            float mu = ls.g.red[0] * (1.f / 2048.f); __syncthreads();
            float l2 = 0.f;
            #pragma unroll
            for (int ii = 0; ii < 8; ++ii) { float dq = vals[ii] - mu; l2 += dq * dq; }
            ls.g.red[t] = l2; __syncthreads();
            for (int off = 128; off; off >>= 1) { if (t < off) ls.g.red[t] += ls.g.red[t + off]; __syncthreads(); }
            float rstd = 1.f / sqrtf(ls.g.red[0] * (1.f / 2048.f) + 1e-5f);
            float* trow = trace + ((size_t)gb * MM + (tick % MM)) * DD;
            #pragma unroll
            for (int ii = 0; ii < 8; ++ii) {
                int d = t + ii * 256;
                astore(&trow[d], (vals[ii] - mu) * rstd * ln_g[d] + ln_b[d]);
            }
        }
        gbar(bar);

        // ========== P4: nlm (thread per (b,d), bid<256) ==========
        if (tick < TT && bid < 256) {
            int i = bid * 256 + t;
            int b4 = i >> 11, d = i & 2047;
            float hp[32];
            #pragma unroll
            for (int hh = 0; hh < 32; hh++) hp[hh] = b1[d * 32 + hh];
            const float* tr = trace + (size_t)b4 * MM * DD;
            for (int m = 0; m < 25; m++) {
                int mph = (tick + 1 + m) % 25;
                float tv = aload(&tr[mph * DD + d]);
                #pragma unroll
                for (int hh = 0; hh < 32; hh++) hp[hh] += tv * w1[((size_t)m * 32 + hh) * DD + d];
            }
            float o0 = b2[d * 2], o1 = b2[d * 2 + 1];
            #pragma unroll
            for (int hh = 0; hh < 16; hh++) {
                float hv = hp[hh] * (1.f / (1.f + expf(-hp[hh + 16])));
                o0 += hv * w2[((size_t)hh * 2) * DD + d];
                o1 += hv * w2[((size_t)hh * 2 + 1) * DD + d];
            }
            astore(&act[i], o0 * (1.f / (1.f + expf(-o1))));
        }
        gbar(bar);
    }
}

// ---------------------------------------------------------------------------
extern "C" void kernel_launch(void* const* d_in, const int* in_sizes, int n_in,
                              void* d_out, int out_size, void* d_ws, size_t ws_size,
                              hipStream_t stream)
{
    const float* x        = (const float*)d_in[0];
    const float* kv_w     = (const float*)d_in[1];
    const float* kv_b     = (const float*)d_in[2];
    const float* ln_kv_g  = (const float*)d_in[3];
    const float* ln_kv_b  = (const float*)d_in[4];
    const float* q_w      = (const float*)d_in[5];
    const float* q_b      = (const float*)d_in[6];
    const float* Wq       = (const float*)d_in[7];
    const float* bq       = (const float*)d_in[8];
    const float* Wk       = (const float*)d_in[9];
    const float* bk       = (const float*)d_in[10];
    const float* Wv       = (const float*)d_in[11];
    const float* bv       = (const float*)d_in[12];
    const float* Wo       = (const float*)d_in[13];
    const float* bo       = (const float*)d_in[14];
    const float* syn_w    = (const float*)d_in[15];
    const float* syn_b    = (const float*)d_in[16];
    const float* ln_syn_g = (const float*)d_in[17];
    const float* ln_syn_b = (const float*)d_in[18];
    const float* nlm_w1   = (const float*)d_in[19];
    const float* nlm_b1   = (const float*)d_in[20];
    const float* nlm_w2   = (const float*)d_in[21];
    const float* nlm_b2   = (const float*)d_in[22];
    const float* out_w    = (const float*)d_in[23];
    const float* out_b    = (const float*)d_in[24];
    const float* dec_a    = (const float*)d_in[25];
    const float* dec_o    = (const float*)d_in[26];
    const float* start_tr = (const float*)d_in[27];
    const float* start_ac = (const float*)d_in[28];
    const int*   idx_la   = (const int*)d_in[29];
    const int*   idx_ra   = (const int*)d_in[30];
    const int*   idx_lo   = (const int*)d_in[31];
    const int*   idx_ro   = (const int*)d_in[32];
    float* out = (float*)d_out;

    // workspace carve (floats)
    float* w = (float*)d_ws;
    float* kvbuf = w;            w += (size_t)8192 * 512;
    float* khT   = w;            w += (size_t)8192 * 512;
    float* vhb   = w;            w += (size_t)8192 * 512;
    float* Wqq   = w;            w += (size_t)512 * 512;
    float* bqq   = w;            w += 512;
    float* W2    = w;            w += (size_t)512 * 4096;
    float* bias2 = w;            w += 4096;
    float* r_a   = w;            w += 512;
    float* r_o   = w;            w += 512;
    float* aab   = w;            w += 2 * BB * NSA;
    float* bab   = w;            w += 2 * BB * NSA;
    float* aob   = w;            w += 2 * BB * NSO;
    float* bob   = w;            w += 2 * BB * NSO;
    float* act   = w;            w += BB * DD;
    float* trace = w;            w += (size_t)BB * MM * DD;
    float* obuf  = w;            w += BB * DIN;
    float* upart = w;            w += (size_t)16 * 32 * 4096;
    float* predbuf = w;          w += BB * NOUT;
    unsigned* bar = (unsigned*)w; w += 16;

    // ---- precompute ----
    init_kernel<<<6400, 256, 0, stream>>>(dec_a, dec_o, start_ac, start_tr, idx_lo, idx_ro,
                                          r_a, r_o, aab, bab, aob, bob, act, trace, bar);
    gemm64<1, 0><<<dim3(128, 8), 256, 0, stream>>>(x, kv_w, kv_b, kvbuf, 8192, 512, 512);
    ln_rows<<<8192, 256, 0, stream>>>(kvbuf, ln_kv_g, ln_kv_b);
    gemm64<0, 1><<<dim3(128, 8), 256, 0, stream>>>(kvbuf, Wk, bk, khT, 8192, 512, 512);
    gemm64<0, 2><<<dim3(128, 8), 256, 0, stream>>>(kvbuf, Wv, bv, vhb, 8192, 512, 512);
    gemm64<0, 0><<<dim3(8, 8), 256, 0, stream>>>(q_w, Wq, nullptr, Wqq, 512, 512, 512);
    bqq_kernel<<<2, 256, 0, stream>>>(q_b, Wq, bq, bqq);
    gemm64<0, 0><<<dim3(8, 64), 256, 0, stream>>>(Wo, syn_w, nullptr, W2, 512, 4096, 512);
    bias2_kernel<<<16, 256, 0, stream>>>(bo, syn_w, syn_b, bias2);

    float* out_sync = out + (size_t)BB * NOUT * TT + (size_t)BB * 2 * TT;

    // ---- persistent 50-tick loop ----
    mega_kernel<<<NBLK, 256, 0, stream>>>(Wqq, bqq, khT, vhb, W2, syn_w, bias2,
                                          ln_syn_g, ln_syn_b,
                                          nlm_w1, nlm_b1, nlm_w2, nlm_b2,
                                          out_w, out_b, r_a, r_o,
                                          idx_la, idx_ra, idx_lo, idx_ro,
                                          aab, bab, aob, bob,
                                          act, trace, obuf, upart,
                                          predbuf, out, out_sync, bar);
}

// Round 4
// 18831.247 us; speedup vs baseline: 2.0124x; 1.1064x over previous
//
#include <hip/hip_runtime.h>
#include <math.h>

// Problem constants
#define BB 32
#define CC 512
#define SS 256
#define DD 2048
#define DIN 512
#define NH 8
#define DHD 64
#define TT 50
#define MM 25
#define NSA 512
#define NSO 512
#define NOUT 1000
#define NBLK 512

typedef float vfloat4 __attribute__((ext_vector_type(4)));

// ---------------------------------------------------------------------------
// Coherent-point access. Loads: batched asm (sc0 sc1 bypass L1/L2 -> fabric),
// ONE waitcnt per batch instead of compiler-serialized per-load round trips.
// Stores: relaxed agent atomics (write-through), drained at barrier vmcnt.
// ---------------------------------------------------------------------------
__device__ __forceinline__ void cload_f4x4(const float* p0, const float* p1,
                                           const float* p2, const float* p3,
                                           vfloat4& v0, vfloat4& v1, vfloat4& v2, vfloat4& v3)
{
    asm volatile(
        "global_load_dwordx4 %0, %4, off sc0 sc1\n\t"
        "global_load_dwordx4 %1, %5, off sc0 sc1\n\t"
        "global_load_dwordx4 %2, %6, off sc0 sc1\n\t"
        "global_load_dwordx4 %3, %7, off sc0 sc1\n\t"
        "s_waitcnt vmcnt(0)"
        : "=&v"(v0), "=&v"(v1), "=&v"(v2), "=&v"(v3)
        : "v"(p0), "v"(p1), "v"(p2), "v"(p3)
        : "memory");
}
__device__ __forceinline__ void cload_f4x2(const float* p0, const float* p1,
                                           vfloat4& v0, vfloat4& v1)
{
    asm volatile(
        "global_load_dwordx4 %0, %2, off sc0 sc1\n\t"
        "global_load_dwordx4 %1, %3, off sc0 sc1\n\t"
        "s_waitcnt vmcnt(0)"
        : "=&v"(v0), "=&v"(v1)
        : "v"(p0), "v"(p1)
        : "memory");
}
__device__ __forceinline__ void cload_f1x4(const float* p0, const float* p1,
                                           const float* p2, const float* p3,
                                           float& v0, float& v1, float& v2, float& v3)
{
    asm volatile(
        "global_load_dword %0, %4, off sc0 sc1\n\t"
        "global_load_dword %1, %5, off sc0 sc1\n\t"
        "global_load_dword %2, %6, off sc0 sc1\n\t"
        "global_load_dword %3, %7, off sc0 sc1\n\t"
        "s_waitcnt vmcnt(0)"
        : "=&v"(v0), "=&v"(v1), "=&v"(v2), "=&v"(v3)
        : "v"(p0), "v"(p1), "v"(p2), "v"(p3)
        : "memory");
}
__device__ __forceinline__ void astore(float* p, float v) {
    __hip_atomic_store(p, v, __ATOMIC_RELAXED, __HIP_MEMORY_SCOPE_AGENT);
}
__device__ __forceinline__ void astore2(float* p, float a, float b) {
    union { float f[2]; unsigned long long u; } x; x.f[0] = a; x.f[1] = b;
    __hip_atomic_store((unsigned long long*)p, x.u, __ATOMIC_RELAXED, __HIP_MEMORY_SCOPE_AGENT);
}
__device__ __forceinline__ void aadd(float* p, float v) {
    unsafeAtomicAdd(p, v);   // global_atomic_add_f32, fire-and-forget
}

// ---------------------------------------------------------------------------
// Init: decays, per-block private sync state, act0, private traces, upart=0
// ---------------------------------------------------------------------------
__global__ void init_kernel(const float* __restrict__ dec_a, const float* __restrict__ dec_o,
                            const float* __restrict__ start_act, const float* __restrict__ start_trace,
                            const int* __restrict__ idx_lo, const int* __restrict__ idx_ro,
                            float* __restrict__ r_a, float* __restrict__ r_o,
                            float* __restrict__ aabP, float* __restrict__ babP,
                            float* __restrict__ aobP, float* __restrict__ bobP,
                            float* __restrict__ act, float* __restrict__ ptrace,
                            float* __restrict__ upart, unsigned* __restrict__ bar)
{
    int i = blockIdx.x * 256 + threadIdx.x;
    if (i < 2) bar[i] = 0u;
    if (i < 512) {
        r_a[i] = expf(-fminf(fmaxf(dec_a[i], 0.f), 15.f));
        r_o[i] = expf(-fminf(fmaxf(dec_o[i], 0.f), 15.f));
    }
    if (i < 256 * 512) {             // per-block private sync states (256 A + 256 B blocks)
        aabP[i] = 0.f; babP[i] = 0.f;
        int j = i & 511;
        aobP[i] = start_act[idx_lo[j]] * start_act[idx_ro[j]];
        bobP[i] = 1.f;
        upart[i] = 0.f;              // 32*4096 accumulator (also 131072)
    }
    if (i < BB * DD) act[i] = start_act[i & (DD - 1)];
    if (i < 256 * MM * 256) {        // private trace: [pb][m][256], pb=(b*8+slice)
        int pb = i / (MM * 256), rem = i % (MM * 256);
        int m = rem >> 8, dl = rem & 255;
        int d = (pb & 7) * 256 + dl;
        ptrace[i] = start_trace[d * MM + m];
    }
}

// ---------------------------------------------------------------------------
// Precompute GEMMs (verbatim, validated round 1)
// ---------------------------------------------------------------------------
template<int AMODE, int SMODE>
__global__ void gemm64(const float* __restrict__ A, const float* __restrict__ Bm,
                       const float* __restrict__ bias, float* __restrict__ Cm,
                       int Mdim, int Ndim, int Kdim)
{
    __shared__ float As[16 * 65];
    __shared__ float Bs[16 * 64];
    int row0 = blockIdx.x * 64;
    int col0 = blockIdx.y * 64;
    int t = threadIdx.x;
    int tx = t & 15, ty = t >> 4;
    float acc[4][4] = {};
    for (int k0 = 0; k0 < Kdim; k0 += 16) {
        if (AMODE == 0) {
            for (int i = t; i < 1024; i += 256) {
                int kk = i & 15, r = i >> 4;
                As[kk * 65 + r] = A[(size_t)(row0 + r) * Kdim + k0 + kk];
            }
        } else {
            int b = row0 / SS, s0 = row0 % SS;
            for (int i = t; i < 1024; i += 256) {
                int r = i & 63, kk = i >> 6;
                As[kk * 65 + r] = A[((size_t)b * CC + k0 + kk) * SS + s0 + r];
            }
        }
        for (int i = t; i < 1024; i += 256) {
            int c = i & 63, kk = i >> 6;
            Bs[kk * 64 + c] = Bm[(size_t)(k0 + kk) * Ndim + col0 + c];
        }
        __syncthreads();
        #pragma unroll
        for (int kk = 0; kk < 16; ++kk) {
            float a[4], bb[4];
            #pragma unroll
            for (int i = 0; i < 4; i++) a[i] = As[kk * 65 + ty * 4 + i];
            #pragma unroll
            for (int j = 0; j < 4; j++) bb[j] = Bs[kk * 64 + tx * 4 + j];
            #pragma unroll
            for (int i = 0; i < 4; i++)
                #pragma unroll
                for (int j = 0; j < 4; j++) acc[i][j] += a[i] * bb[j];
        }
        __syncthreads();
    }
    #pragma unroll
    for (int i = 0; i < 4; i++)
        #pragma unroll
        for (int j = 0; j < 4; j++) {
            int row = row0 + ty * 4 + i, col = col0 + tx * 4 + j;
            float v = acc[i][j] + (bias ? bias[col] : 0.f);
            if (SMODE == 0) {
                Cm[(size_t)row * Ndim + col] = v;
            } else if (SMODE == 1) {
                int b = row / SS, s = row % SS, h = col >> 6, dh = col & 63;
                Cm[(((size_t)b * NH + h) * DHD + dh) * SS + s] = v;
            } else {
                int b = row / SS, s = row % SS, h = col >> 6, dh = col & 63;
                Cm[(((size_t)b * NH + h) * SS + s) * DHD + dh] = v;
            }
        }
}

__global__ void ln_rows(float* __restrict__ buf, const float* __restrict__ g,
                        const float* __restrict__ bta)
{
    int row = blockIdx.x, t = threadIdx.x;
    __shared__ float red[256];
    float v0 = buf[(size_t)row * 512 + t];
    float v1 = buf[(size_t)row * 512 + 256 + t];
    red[t] = v0 + v1; __syncthreads();
    for (int off = 128; off; off >>= 1) { if (t < off) red[t] += red[t + off]; __syncthreads(); }
    float mu = red[0] * (1.f / 512.f); __syncthreads();
    float d0 = v0 - mu, d1 = v1 - mu;
    red[t] = d0 * d0 + d1 * d1; __syncthreads();
    for (int off = 128; off; off >>= 1) { if (t < off) red[t] += red[t + off]; __syncthreads(); }
    float rstd = 1.f / sqrtf(red[0] * (1.f / 512.f) + 1e-5f);
    buf[(size_t)row * 512 + t]       = d0 * rstd * g[t] + bta[t];
    buf[(size_t)row * 512 + 256 + t] = d1 * rstd * g[t + 256] + bta[t + 256];
}

__global__ void bqq_kernel(const float* __restrict__ q_b, const float* __restrict__ Wq,
                           const float* __restrict__ bq, float* __restrict__ bqq)
{
    int c = blockIdx.x * 256 + threadIdx.x;
    if (c >= 512) return;
    float acc = bq[c];
    for (int k = 0; k < 512; k++) acc += q_b[k] * Wq[k * 512 + c];
    bqq[c] = acc;
}

__global__ void bias2_kernel(const float* __restrict__ bo, const float* __restrict__ syn_w,
                             const float* __restrict__ syn_b, float* __restrict__ bias2)
{
    int c = blockIdx.x * 256 + threadIdx.x;
    if (c >= 4096) return;
    float acc = syn_b[c];
    for (int k = 0; k < 512; k++) acc += bo[k] * syn_w[(size_t)k * 4096 + c];
    bias2[c] = acc;
}

// ---------------------------------------------------------------------------
// Fence-free grid barrier: drain vmcnt (all coherent stores + atomics acked
// at fabric), then relaxed monotone counter. 512 blocks, 2/CU co-resident.
// ---------------------------------------------------------------------------
__device__ __forceinline__ void gbar(unsigned* bar)
{
    asm volatile("s_waitcnt vmcnt(0)" ::: "memory");
    __syncthreads();
    if (threadIdx.x == 0) {
        unsigned arr = __hip_atomic_fetch_add(&bar[0], 1u, __ATOMIC_RELAXED, __HIP_MEMORY_SCOPE_AGENT);
        unsigned tgt = arr / (unsigned)NBLK + 1u;
        if ((arr % (unsigned)NBLK) == (unsigned)NBLK - 1u)
            __hip_atomic_store(&bar[1], tgt, __ATOMIC_RELAXED, __HIP_MEMORY_SCOPE_AGENT);
        while (__hip_atomic_load(&bar[1], __ATOMIC_RELAXED, __HIP_MEMORY_SCOPE_AGENT) < tgt)
            __builtin_amdgcn_s_sleep(2);
    }
    __syncthreads();
}

union LDSU {
    struct { float syncA[512]; float qs[64]; float red[256]; float ps[256]; } a;  // P1 A
    struct { float so[512]; float red[256]; } b;                                   // P1 B
    struct { float As[320 * 35]; } s;                                              // P2 syn (44.8 KB)
    struct { float st[2048]; float red[256]; } g;                                  // P34
};

// ---------------------------------------------------------------------------
// Persistent mega-kernel: 50 ticks, 3 barriers/tick
// ---------------------------------------------------------------------------
__global__ void __launch_bounds__(256, 2)
mega_kernel(const float* __restrict__ Wqq, const float* __restrict__ bqq,
            const float* __restrict__ khT, const float* __restrict__ vh,
            const float* __restrict__ W2, const float* __restrict__ syn_w,
            const float* __restrict__ bias2,
            const float* __restrict__ ln_g, const float* __restrict__ ln_b,
            const float* __restrict__ w1, const float* __restrict__ b1,
            const float* __restrict__ w2, const float* __restrict__ b2,
            const float* __restrict__ out_w, const float* __restrict__ out_b,
            const float* __restrict__ r_a, const float* __restrict__ r_o,
            const int* __restrict__ la, const int* __restrict__ ra,
            const int* __restrict__ lo, const int* __restrict__ ro,
            float* aabP, float* babP, float* aobP, float* bobP,
            float* act, float* ptrace, float* obuf, float* upart,
            float* predbuf, float* out, float* out_sync, unsigned* bar)
{
    __shared__ LDSU ls;
    const int bid = blockIdx.x;
    const int t = threadIdx.x;
    const int b = (bid & 255) >> 3, h = bid & 7;

    for (int tick = 0; tick <= TT; ++tick) {
        // ===== P1: A (bid<256): sync_a+qh+attn, zero upart | B: sync_o(t-1)+pred(t-1) =====
        if (bid < 256 && tick < TT) {
            const float* actb = act + b * DD;
            {   // action sync, private state, one batched coherent gather
                float al0, ar0, al1, ar1;
                cload_f1x4(actb + la[t], actb + ra[t], actb + la[t + 256], actb + ra[t + 256],
                           al0, ar0, al1, ar1);
                float* AA = aabP + bid * 512; float* BA = babP + bid * 512;
                float aa0 = r_a[t] * AA[t] + al0 * ar0;            AA[t] = aa0;
                float bb0 = r_a[t] * BA[t] + 1.f;                  BA[t] = bb0;
                ls.a.syncA[t] = aa0 / sqrtf(bb0);
                float aa1 = r_a[t + 256] * AA[t + 256] + al1 * ar1; AA[t + 256] = aa1;
                float bb1 = r_a[t + 256] * BA[t + 256] + 1.f;       BA[t + 256] = bb1;
                ls.a.syncA[t + 256] = aa1 / sqrtf(bb1);
            }
            __syncthreads();
            {   // qh for head h
                int cl = t & 63, kq = t >> 6;
                const float* wp = Wqq + (size_t)(kq * 128) * 512 + h * 64 + cl;
                const float* sp = ls.a.syncA + kq * 128;
                float part = 0.f;
                #pragma unroll 8
                for (int k = 0; k < 128; ++k) part += sp[k] * wp[(size_t)k * 512];
                ls.a.red[t] = part;
            }
            __syncthreads();
            if (t < 64)
                ls.a.qs[t] = ls.a.red[t] + ls.a.red[t + 64] + ls.a.red[t + 128] + ls.a.red[t + 192]
                           + bqq[h * 64 + t];
            __syncthreads();
            {   // attention for (b,h)
                const float* kb = khT + (size_t)bid * 64 * 256;   // [dh][s]
                float sc = 0.f;
                #pragma unroll 8
                for (int dh = 0; dh < 64; ++dh) sc += ls.a.qs[dh] * kb[dh * 256 + t];
                sc *= 0.125f;
                ls.a.red[t] = sc; __syncthreads();
                for (int off = 128; off; off >>= 1) { if (t < off) ls.a.red[t] = fmaxf(ls.a.red[t], ls.a.red[t + off]); __syncthreads(); }
                float mx = ls.a.red[0]; __syncthreads();
                float e = expf(sc - mx);
                ls.a.red[t] = e; __syncthreads();
                for (int off = 128; off; off >>= 1) { if (t < off) ls.a.red[t] += ls.a.red[t + off]; __syncthreads(); }
                float inv = 1.f / ls.a.red[0];
                ls.a.ps[t] = e * inv;
                __syncthreads();
                int dh = t & 63, ch = t >> 6;
                const float* vb = vh + (size_t)bid * 256 * 64;    // [s][dh]
                float acc2 = 0.f;
                for (int s2 = ch * 64; s2 < ch * 64 + 64; ++s2) acc2 += ls.a.ps[s2] * vb[s2 * 64 + dh];
                ls.a.red[t] = acc2; __syncthreads();
                if (t < 128) ls.a.red[t] += ls.a.red[t + 128];
                __syncthreads();
                if (t < 64) astore(&obuf[b * 512 + h * 64 + t], ls.a.red[t] + ls.a.red[t + 64]);
            }
            astore2(&upart[bid * 512 + 2 * t], 0.f, 0.f);   // zero accumulator for P2
        }
        if (bid >= 256 && tick > 0) {   // B: sync_o(s) + pred(s), s = tick-1; ctile = h
            const int s = tick - 1;
            const float* actb = act + b * DD;
            float al0, ar0, al1, ar1;
            cload_f1x4(actb + lo[t], actb + ro[t], actb + lo[t + 256], actb + ro[t + 256],
                       al0, ar0, al1, ar1);
            float* AO = aobP + (bid & 255) * 512; float* BO = bobP + (bid & 255) * 512;
            float aa0 = r_o[t] * AO[t] + al0 * ar0;            AO[t] = aa0;
            float bb0 = r_o[t] * BO[t] + 1.f;                  BO[t] = bb0;
            float sv0 = aa0 / sqrtf(bb0);
            ls.b.so[t] = sv0;
            float aa1 = r_o[t + 256] * AO[t + 256] + al1 * ar1; AO[t + 256] = aa1;
            float bb1 = r_o[t + 256] * BO[t + 256] + 1.f;       BO[t + 256] = bb1;
            float sv1 = aa1 / sqrtf(bb1);
            ls.b.so[t + 256] = sv1;
            if (s == TT - 1 && h == 0) {
                out_sync[b * 512 + t] = sv0;
                out_sync[b * 512 + t + 256] = sv1;
            }
            __syncthreads();
            {   // pred: 125 cols for (b, ctile=h), K halves of 256
                int cl = t & 127, kh2 = t >> 7;
                float part = 0.f;
                if (cl < 125) {
                    int c = h * 125 + cl;
                    const float* wp = out_w + (size_t)(kh2 * 256) * 1000 + c;
                    const float* sp = ls.b.so + kh2 * 256;
                    #pragma unroll 8
                    for (int k = 0; k < 256; ++k) part += sp[k] * wp[(size_t)k * 1000];
                }
                ls.b.red[t] = part;
            }
            __syncthreads();
            if (t < 125) {
                int c = h * 125 + t;
                float v = ls.b.red[t] + ls.b.red[t + 128] + out_b[c];
                astore(&predbuf[b * 1000 + c], v);
                out[(size_t)b * NOUT * TT + (size_t)c * TT + s] = v;
            }
        }
        gbar(bar);

        // ===== P2: syn GEMM, 512 units (64 ntile x 8 ksplit), atomic-add partials =====
        if (tick < TT) {
            const int nt0 = (bid & 63) * 64;
            const int k0 = (bid >> 6) * 320;
            // batched coherent staging of A (obuf||act), 10 float4/thread, 3 waits
            vfloat4 stg[10]; const float* sp[10];
            #pragma unroll
            for (int j = 0; j < 10; ++j) {
                int idx = t + j * 256;
                int r = idx / 80, c4 = idx % 80;
                int g = k0 + c4 * 4;
                sp[j] = (g < 512) ? (obuf + r * 512 + g) : (act + r * 2048 + (g - 512));
            }
            cload_f4x4(sp[0], sp[1], sp[2], sp[3], stg[0], stg[1], stg[2], stg[3]);
            cload_f4x4(sp[4], sp[5], sp[6], sp[7], stg[4], stg[5], stg[6], stg[7]);
            cload_f4x2(sp[8], sp[9], stg[8], stg[9]);
            #pragma unroll
            for (int j = 0; j < 10; ++j) {
                int idx = t + j * 256;
                int r = idx / 80, c4 = idx % 80;
                #pragma unroll
                for (int cc = 0; cc < 4; ++cc)
                    ls.s.As[(c4 * 4 + cc) * 35 + r] = stg[j][cc];
            }
            __syncthreads();
            const int ct = t & 15, rt = t >> 4;
            const int c0 = nt0 + ct * 4, r0 = rt * 2;
            float acc0[4] = {}, acc1[4] = {};
            #pragma unroll 4
            for (int k = 0; k < 320; ++k) {
                int kk = k0 + k;
                const float* wr2 = (kk < 512 ? W2 : syn_w) + (size_t)kk * 4096 + c0;
                vfloat4 w4 = *(const vfloat4*)wr2;
                float a0 = ls.s.As[k * 35 + r0];
                float a1 = ls.s.As[k * 35 + r0 + 1];
                #pragma unroll
                for (int j = 0; j < 4; ++j) { acc0[j] += a0 * w4[j]; acc1[j] += a1 * w4[j]; }
            }
            #pragma unroll
            for (int j = 0; j < 4; ++j) {
                aadd(&upart[(size_t)r0 * 4096 + c0 + j], acc0[j]);
                aadd(&upart[(size_t)(r0 + 1) * 4096 + c0 + j], acc1[j]);
            }
            __syncthreads();
        }
        gbar(bar);

        // ===== P34: fused GLU+LN+NLM (bid<256, block=(b,slice)) | cert on bid 256..287 =====
        if (tick < TT && bid < 256) {
            const int slice = h;                 // bid & 7
            const float* ub = upart + b * 4096;
            vfloat4 u0, u1, u2, u3;
            cload_f4x4(ub + 4 * t, ub + 4 * t + 1024, ub + 4 * t + 2048, ub + 4 * t + 3072,
                       u0, u1, u2, u3);
            float g0[4], g1[4]; float loc = 0.f;
            #pragma unroll
            for (int c = 0; c < 4; ++c) {
                int d0 = 4 * t + c, d1 = 1024 + 4 * t + c;
                float a0 = u0[c] + bias2[d0], bb0 = u2[c] + bias2[d0 + 2048];
                float a1 = u1[c] + bias2[d1], bb1 = u3[c] + bias2[d1 + 2048];
                g0[c] = a0 * (1.f / (1.f + expf(-bb0)));
                g1[c] = a1 * (1.f / (1.f + expf(-bb1)));
                loc += g0[c] + g1[c];
            }
            ls.g.red[t] = loc; __syncthreads();
            for (int off = 128; off; off >>= 1) { if (t < off) ls.g.red[t] += ls.g.red[t + off]; __syncthreads(); }
            float mu = ls.g.red[0] * (1.f / 2048.f); __syncthreads();
            float l2 = 0.f;
            #pragma unroll
            for (int c = 0; c < 4; ++c) {
                float dq0 = g0[c] - mu, dq1 = g1[c] - mu;
                l2 += dq0 * dq0 + dq1 * dq1;
            }
            ls.g.red[t] = l2; __syncthreads();
            for (int off = 128; off; off >>= 1) { if (t < off) ls.g.red[t] += ls.g.red[t + off]; __syncthreads(); }
            float rstd = 1.f / sqrtf(ls.g.red[0] * (1.f / 2048.f) + 1e-5f);
            __syncthreads();
            #pragma unroll
            for (int c = 0; c < 4; ++c) {
                int d0 = 4 * t + c, d1 = 1024 + 4 * t + c;
                ls.g.st[d0] = (g0[c] - mu) * rstd * ln_g[d0] + ln_b[d0];
                ls.g.st[d1] = (g1[c] - mu) * rstd * ln_g[d1] + ln_b[d1];
            }
            __syncthreads();
            // NLM for neuron d = slice*256 + t; trace is BLOCK-PRIVATE (normal cached)
            const int d = slice * 256 + t;
            float sv = ls.g.st[d];
            float* ptr = ptrace + (size_t)bid * (MM * 256);
            ptr[(tick % MM) * 256 + t] = sv;
            float hp[32];
            #pragma unroll
            for (int hh = 0; hh < 32; hh++) hp[hh] = b1[d * 32 + hh];
            for (int m = 0; m < MM; m++) {
                int mph = (tick + 1 + m) % MM;
                float tv = ptr[mph * 256 + t];
                #pragma unroll
                for (int hh = 0; hh < 32; hh++) hp[hh] += tv * w1[((size_t)m * 32 + hh) * DD + d];
            }
            float o0 = b2[d * 2], o1 = b2[d * 2 + 1];
            #pragma unroll
            for (int hh = 0; hh < 16; hh++) {
                float hv = hp[hh] * (1.f / (1.f + expf(-hp[hh + 16])));
                o0 += hv * w2[((size_t)hh * 2) * DD + d];
                o1 += hv * w2[((size_t)hh * 2 + 1) * DD + d];
            }
            astore(&act[b * DD + d], o0 * (1.f / (1.f + expf(-o1))));
        }
        if (tick > 0 && bid >= 256 && bid < 288) {   // cert(s), s = tick-1
            const int s = tick - 1;
            const int b2 = bid - 256;
            const float* pb_ = predbuf + b2 * 1000;
            float v0, v1, v2, v3;
            const float* p3 = (t < 232) ? (pb_ + t + 768) : pb_;
            cload_f1x4(pb_ + t, pb_ + t + 256, pb_ + t + 512, p3, v0, v1, v2, v3);
            float pv[4] = { v0, v1, v2, (t < 232) ? v3 : -1e30f };
            float mx = fmaxf(fmaxf(pv[0], pv[1]), fmaxf(pv[2], pv[3]));
            ls.g.red[t] = mx; __syncthreads();
            for (int off = 128; off; off >>= 1) { if (t < off) ls.g.red[t] = fmaxf(ls.g.red[t], ls.g.red[t + off]); __syncthreads(); }
            mx = ls.g.red[0]; __syncthreads();
            float s1 = 0.f, s2 = 0.f;
            #pragma unroll
            for (int ii = 0; ii < 4; ++ii) {
                int c = t + ii * 256;
                if (c < 1000) { float xx = pv[ii] - mx; float e = expf(xx); s1 += e; s2 += e * xx; }
            }
            ls.g.red[t] = s1; __syncthreads();
            for (int off = 128; off; off >>= 1) { if (t < off) ls.g.red[t] += ls.g.red[t + off]; __syncthreads(); }
            s1 = ls.g.red[0]; __syncthreads();
            ls.g.red[t] = s2; __syncthreads();
            for (int off = 128; off; off >>= 1) { if (t < off) ls.g.red[t] += ls.g.red[t + off]; __syncthreads(); }
            s2 = ls.g.red[0];
            if (t == 0) {
                float ne = -(s2 / s1 - logf(s1)) * (1.f / logf(1000.f));
                size_t base = (size_t)BB * NOUT * TT + (size_t)b2 * 2 * TT + s;
                out[base] = ne;
                out[base + TT] = 1.f - ne;
            }
        }
        gbar(bar);
    }
}

// ---------------------------------------------------------------------------
extern "C" void kernel_launch(void* const* d_in, const int* in_sizes, int n_in,
                              void* d_out, int out_size, void* d_ws, size_t ws_size,
                              hipStream_t stream)
{
    const float* x        = (const float*)d_in[0];
    const float* kv_w     = (const float*)d_in[1];
    const float* kv_b     = (const float*)d_in[2];
    const float* ln_kv_g  = (const float*)d_in[3];
    const float* ln_kv_b  = (const float*)d_in[4];
    const float* q_w      = (const float*)d_in[5];
    const float* q_b      = (const float*)d_in[6];
    const float* Wq       = (const float*)d_in[7];
    const float* bq       = (const float*)d_in[8];
    const float* Wk       = (const float*)d_in[9];
    const float* bk       = (const float*)d_in[10];
    const float* Wv       = (const float*)d_in[11];
    const float* bv       = (const float*)d_in[12];
    const float* Wo       = (const float*)d_in[13];
    const float* bo       = (const float*)d_in[14];
    const float* syn_w    = (const float*)d_in[15];
    const float* syn_b    = (const float*)d_in[16];
    const float* ln_syn_g = (const float*)d_in[17];
    const float* ln_syn_b = (const float*)d_in[18];
    const float* nlm_w1   = (const float*)d_in[19];
    const float* nlm_b1   = (const float*)d_in[20];
    const float* nlm_w2   = (const float*)d_in[21];
    const float* nlm_b2   = (const float*)d_in[22];
    const float* out_w    = (const float*)d_in[23];
    const float* out_b    = (const float*)d_in[24];
    const float* dec_a    = (const float*)d_in[25];
    const float* dec_o    = (const float*)d_in[26];
    const float* start_tr = (const float*)d_in[27];
    const float* start_ac = (const float*)d_in[28];
    const int*   idx_la   = (const int*)d_in[29];
    const int*   idx_ra   = (const int*)d_in[30];
    const int*   idx_lo   = (const int*)d_in[31];
    const int*   idx_ro   = (const int*)d_in[32];
    float* out = (float*)d_out;

    // workspace carve (floats)
    float* w = (float*)d_ws;
    float* kvbuf  = w;            w += (size_t)8192 * 512;
    float* khT    = w;            w += (size_t)8192 * 512;
    float* vhb    = w;            w += (size_t)8192 * 512;
    float* Wqq    = w;            w += (size_t)512 * 512;
    float* bqq    = w;            w += 512;
    float* W2     = w;            w += (size_t)512 * 4096;
    float* bias2  = w;            w += 4096;
    float* r_a    = w;            w += 512;
    float* r_o    = w;            w += 512;
    float* aabP   = w;            w += (size_t)256 * 512;
    float* babP   = w;            w += (size_t)256 * 512;
    float* aobP   = w;            w += (size_t)256 * 512;
    float* bobP   = w;            w += (size_t)256 * 512;
    float* act    = w;            w += BB * DD;
    float* ptrace = w;            w += (size_t)256 * MM * 256;
    float* obuf   = w;            w += BB * DIN;
    float* upart  = w;            w += (size_t)32 * 4096;
    float* predbuf= w;            w += BB * NOUT;
    unsigned* bar = (unsigned*)w; w += 16;

    // ---- precompute ----
    init_kernel<<<6400, 256, 0, stream>>>(dec_a, dec_o, start_ac, start_tr, idx_lo, idx_ro,
                                          r_a, r_o, aabP, babP, aobP, bobP, act, ptrace,
                                          upart, bar);
    gemm64<1, 0><<<dim3(128, 8), 256, 0, stream>>>(x, kv_w, kv_b, kvbuf, 8192, 512, 512);
    ln_rows<<<8192, 256, 0, stream>>>(kvbuf, ln_kv_g, ln_kv_b);
    gemm64<0, 1><<<dim3(128, 8), 256, 0, stream>>>(kvbuf, Wk, bk, khT, 8192, 512, 512);
    gemm64<0, 2><<<dim3(128, 8), 256, 0, stream>>>(kvbuf, Wv, bv, vhb, 8192, 512, 512);
    gemm64<0, 0><<<dim3(8, 8), 256, 0, stream>>>(q_w, Wq, nullptr, Wqq, 512, 512, 512);
    bqq_kernel<<<2, 256, 0, stream>>>(q_b, Wq, bq, bqq);
    gemm64<0, 0><<<dim3(8, 64), 256, 0, stream>>>(Wo, syn_w, nullptr, W2, 512, 4096, 512);
    bias2_kernel<<<16, 256, 0, stream>>>(bo, syn_w, syn_b, bias2);

    float* out_sync = out + (size_t)BB * NOUT * TT + (size_t)BB * 2 * TT;

    // ---- persistent 50-tick loop ----
    mega_kernel<<<NBLK, 256, 0, stream>>>(Wqq, bqq, khT, vhb, W2, syn_w, bias2,
                                          ln_syn_g, ln_syn_b,
                                          nlm_w1, nlm_b1, nlm_w2, nlm_b2,
                                          out_w, out_b, r_a, r_o,
                                          idx_la, idx_ra, idx_lo, idx_ro,
                                          aabP, babP, aobP, bobP,
                                          act, ptrace, obuf, upart,
                                          predbuf, out, out_sync, bar);
}

// Round 5
// 15959.967 us; speedup vs baseline: 2.3744x; 1.1799x over previous
//
#include <hip/hip_runtime.h>
#include <math.h>

// Problem constants
#define BB 32
#define CC 512
#define SS 256
#define DD 2048
#define DIN 512
#define NH 8
#define DHD 64
#define TT 50
#define MM 25
#define NSA 512
#define NSO 512
#define NOUT 1000
#define NBLK 512

typedef float vfloat4 __attribute__((ext_vector_type(4)));

// ---------------------------------------------------------------------------
// Coherent-point access. Loads: batched asm (sc0 sc1 bypass L1/L2 -> fabric),
// ONE waitcnt per batch. Stores: relaxed agent atomics (write-through),
// drained at the barrier's vmcnt(0).
// ---------------------------------------------------------------------------
__device__ __forceinline__ void cload_f4x4(const float* p0, const float* p1,
                                           const float* p2, const float* p3,
                                           vfloat4& v0, vfloat4& v1, vfloat4& v2, vfloat4& v3)
{
    asm volatile(
        "global_load_dwordx4 %0, %4, off sc0 sc1\n\t"
        "global_load_dwordx4 %1, %5, off sc0 sc1\n\t"
        "global_load_dwordx4 %2, %6, off sc0 sc1\n\t"
        "global_load_dwordx4 %3, %7, off sc0 sc1\n\t"
        "s_waitcnt vmcnt(0)"
        : "=&v"(v0), "=&v"(v1), "=&v"(v2), "=&v"(v3)
        : "v"(p0), "v"(p1), "v"(p2), "v"(p3)
        : "memory");
}
__device__ __forceinline__ void cload_f4x2(const float* p0, const float* p1,
                                           vfloat4& v0, vfloat4& v1)
{
    asm volatile(
        "global_load_dwordx4 %0, %2, off sc0 sc1\n\t"
        "global_load_dwordx4 %1, %3, off sc0 sc1\n\t"
        "s_waitcnt vmcnt(0)"
        : "=&v"(v0), "=&v"(v1)
        : "v"(p0), "v"(p1)
        : "memory");
}
__device__ __forceinline__ void cload_f1x4(const float* p0, const float* p1,
                                           const float* p2, const float* p3,
                                           float& v0, float& v1, float& v2, float& v3)
{
    asm volatile(
        "global_load_dword %0, %4, off sc0 sc1\n\t"
        "global_load_dword %1, %5, off sc0 sc1\n\t"
        "global_load_dword %2, %6, off sc0 sc1\n\t"
        "global_load_dword %3, %7, off sc0 sc1\n\t"
        "s_waitcnt vmcnt(0)"
        : "=&v"(v0), "=&v"(v1), "=&v"(v2), "=&v"(v3)
        : "v"(p0), "v"(p1), "v"(p2), "v"(p3)
        : "memory");
}
__device__ __forceinline__ void astore(float* p, float v) {
    __hip_atomic_store(p, v, __ATOMIC_RELAXED, __HIP_MEMORY_SCOPE_AGENT);
}
__device__ __forceinline__ void astore2(float* p, float a, float b) {
    union { float f[2]; unsigned long long u; } x; x.f[0] = a; x.f[1] = b;
    __hip_atomic_store((unsigned long long*)p, x.u, __ATOMIC_RELAXED, __HIP_MEMORY_SCOPE_AGENT);
}
__device__ __forceinline__ void aadd(float* p, float v) {
    unsafeAtomicAdd(p, v);   // global_atomic_add_f32, device-coherent (validated R3/R4)
}

// ---------------------------------------------------------------------------
// Init: decays, per-block private sync state, act0, private traces, upart=0,
// tree-barrier state (4096 uints)
// ---------------------------------------------------------------------------
__global__ void init_kernel(const float* __restrict__ dec_a, const float* __restrict__ dec_o,
                            const float* __restrict__ start_act, const float* __restrict__ start_trace,
                            const int* __restrict__ idx_lo, const int* __restrict__ idx_ro,
                            float* __restrict__ r_a, float* __restrict__ r_o,
                            float* __restrict__ aabP, float* __restrict__ babP,
                            float* __restrict__ aobP, float* __restrict__ bobP,
                            float* __restrict__ act, float* __restrict__ ptrace,
                            float* __restrict__ upart, unsigned* __restrict__ bar)
{
    int i = blockIdx.x * 256 + threadIdx.x;
    if (i < 4096) bar[i] = 0u;
    if (i < 512) {
        r_a[i] = expf(-fminf(fmaxf(dec_a[i], 0.f), 15.f));
        r_o[i] = expf(-fminf(fmaxf(dec_o[i], 0.f), 15.f));
    }
    if (i < 256 * 512) {             // per-block private sync states (256 A + 256 B blocks)
        aabP[i] = 0.f; babP[i] = 0.f;
        int j = i & 511;
        aobP[i] = start_act[idx_lo[j]] * start_act[idx_ro[j]];
        bobP[i] = 1.f;
        upart[i] = 0.f;              // 32*4096 accumulator (also 131072)
    }
    if (i < BB * DD) act[i] = start_act[i & (DD - 1)];
    if (i < 256 * MM * 256) {        // private trace: [pb][m][256], pb=(b*8+slice)
        int pb = i / (MM * 256), rem = i % (MM * 256);
        int m = rem >> 8, dl = rem & 255;
        int d = (pb & 7) * 256 + dl;
        ptrace[i] = start_trace[d * MM + m];
    }
}

// ---------------------------------------------------------------------------
// Precompute GEMMs (verbatim, validated round 1)
// ---------------------------------------------------------------------------
template<int AMODE, int SMODE>
__global__ void gemm64(const float* __restrict__ A, const float* __restrict__ Bm,
                       const float* __restrict__ bias, float* __restrict__ Cm,
                       int Mdim, int Ndim, int Kdim)
{
    __shared__ float As[16 * 65];
    __shared__ float Bs[16 * 64];
    int row0 = blockIdx.x * 64;
    int col0 = blockIdx.y * 64;
    int t = threadIdx.x;
    int tx = t & 15, ty = t >> 4;
    float acc[4][4] = {};
    for (int k0 = 0; k0 < Kdim; k0 += 16) {
        if (AMODE == 0) {
            for (int i = t; i < 1024; i += 256) {
                int kk = i & 15, r = i >> 4;
                As[kk * 65 + r] = A[(size_t)(row0 + r) * Kdim + k0 + kk];
            }
        } else {
            int b = row0 / SS, s0 = row0 % SS;
            for (int i = t; i < 1024; i += 256) {
                int r = i & 63, kk = i >> 6;
                As[kk * 65 + r] = A[((size_t)b * CC + k0 + kk) * SS + s0 + r];
            }
        }
        for (int i = t; i < 1024; i += 256) {
            int c = i & 63, kk = i >> 6;
            Bs[kk * 64 + c] = Bm[(size_t)(k0 + kk) * Ndim + col0 + c];
        }
        __syncthreads();
        #pragma unroll
        for (int kk = 0; kk < 16; ++kk) {
            float a[4], bb[4];
            #pragma unroll
            for (int i = 0; i < 4; i++) a[i] = As[kk * 65 + ty * 4 + i];
            #pragma unroll
            for (int j = 0; j < 4; j++) bb[j] = Bs[kk * 64 + tx * 4 + j];
            #pragma unroll
            for (int i = 0; i < 4; i++)
                #pragma unroll
                for (int j = 0; j < 4; j++) acc[i][j] += a[i] * bb[j];
        }
        __syncthreads();
    }
    #pragma unroll
    for (int i = 0; i < 4; i++)
        #pragma unroll
        for (int j = 0; j < 4; j++) {
            int row = row0 + ty * 4 + i, col = col0 + tx * 4 + j;
            float v = acc[i][j] + (bias ? bias[col] : 0.f);
            if (SMODE == 0) {
                Cm[(size_t)row * Ndim + col] = v;
            } else if (SMODE == 1) {
                int b = row / SS, s = row % SS, h = col >> 6, dh = col & 63;
                Cm[(((size_t)b * NH + h) * DHD + dh) * SS + s] = v;
            } else {
                int b = row / SS, s = row % SS, h = col >> 6, dh = col & 63;
                Cm[(((size_t)b * NH + h) * SS + s) * DHD + dh] = v;
            }
        }
}

__global__ void ln_rows(float* __restrict__ buf, const float* __restrict__ g,
                        const float* __restrict__ bta)
{
    int row = blockIdx.x, t = threadIdx.x;
    __shared__ float red[256];
    float v0 = buf[(size_t)row * 512 + t];
    float v1 = buf[(size_t)row * 512 + 256 + t];
    red[t] = v0 + v1; __syncthreads();
    for (int off = 128; off; off >>= 1) { if (t < off) red[t] += red[t + off]; __syncthreads(); }
    float mu = red[0] * (1.f / 512.f); __syncthreads();
    float d0 = v0 - mu, d1 = v1 - mu;
    red[t] = d0 * d0 + d1 * d1; __syncthreads();
    for (int off = 128; off; off >>= 1) { if (t < off) red[t] += red[t + off]; __syncthreads(); }
    float rstd = 1.f / sqrtf(red[0] * (1.f / 512.f) + 1e-5f);
    buf[(size_t)row * 512 + t]       = d0 * rstd * g[t] + bta[t];
    buf[(size_t)row * 512 + 256 + t] = d1 * rstd * g[t + 256] + bta[t + 256];
}

__global__ void bqq_kernel(const float* __restrict__ q_b, const float* __restrict__ Wq,
                           const float* __restrict__ bq, float* __restrict__ bqq)
{
    int c = blockIdx.x * 256 + threadIdx.x;
    if (c >= 512) return;
    float acc = bq[c];
    for (int k = 0; k < 512; k++) acc += q_b[k] * Wq[k * 512 + c];
    bqq[c] = acc;
}

__global__ void bias2_kernel(const float* __restrict__ bo, const float* __restrict__ syn_w,
                             const float* __restrict__ syn_b, float* __restrict__ bias2)
{
    int c = blockIdx.x * 256 + threadIdx.x;
    if (c >= 4096) return;
    float acc = syn_b[c];
    for (int k = 0; k < 512; k++) acc += bo[k] * syn_w[(size_t)k * 4096 + c];
    bias2[c] = acc;
}

// ---------------------------------------------------------------------------
// Tree grid barrier (fence-free). 3 levels: 64 leaf counters (8 blocks each)
// -> 8 mid -> 1 root -> broadcast word. All counters monotone; each level's
// RMWs land on DISTINCT 128B lines so serialization is 8 deep per level
// instead of 512 deep on one line (the R3/R4 barrier pathology).
// Layout (uint indices): leaf[g]=g*32, mid[j]=2048+j*32, root=2304+0,
// bcast=2368+0 (separate line so polls don't contend with arrives).
// ---------------------------------------------------------------------------
__device__ __forceinline__ void gbar(unsigned* bar)
{
    asm volatile("s_waitcnt vmcnt(0)" ::: "memory");
    __syncthreads();
    if (threadIdx.x == 0) {
        const int g = blockIdx.x >> 3;   // 64 groups of 8
        unsigned arr0 = __hip_atomic_fetch_add(&bar[g * 32], 1u, __ATOMIC_RELAXED, __HIP_MEMORY_SCOPE_AGENT);
        unsigned tgt = (arr0 >> 3) + 1u;
        if ((arr0 & 7u) == 7u) {
            unsigned arr1 = __hip_atomic_fetch_add(&bar[2048 + (g >> 3) * 32], 1u, __ATOMIC_RELAXED, __HIP_MEMORY_SCOPE_AGENT);
            if ((arr1 & 7u) == 7u) {
                unsigned arr2 = __hip_atomic_fetch_add(&bar[2304], 1u, __ATOMIC_RELAXED, __HIP_MEMORY_SCOPE_AGENT);
                if ((arr2 & 7u) == 7u)
                    __hip_atomic_store(&bar[2368], (arr2 >> 3) + 1u, __ATOMIC_RELAXED, __HIP_MEMORY_SCOPE_AGENT);
            }
        }
        while (__hip_atomic_load(&bar[2368], __ATOMIC_RELAXED, __HIP_MEMORY_SCOPE_AGENT) < tgt)
            __builtin_amdgcn_s_sleep(4);
    }
    __syncthreads();
}

union LDSU {
    struct { float syncA[512]; float qs[64]; float red[256]; float ps[256]; } a;  // P1 A
    struct { float so[512]; float red[256]; } b;                                   // P1 B
    struct { float As[320 * 35]; } s;                                              // P2 syn (44.8 KB)
    struct { float st[2048]; float red[256]; } g;                                  // P34
};

// ---------------------------------------------------------------------------
// Persistent mega-kernel: 50 ticks, 3 tree barriers/tick
// ---------------------------------------------------------------------------
__global__ void __launch_bounds__(256, 2)
mega_kernel(const float* __restrict__ Wqq, const float* __restrict__ bqq,
            const float* __restrict__ khT, const float* __restrict__ vh,
            const float* __restrict__ W2, const float* __restrict__ syn_w,
            const float* __restrict__ bias2,
            const float* __restrict__ ln_g, const float* __restrict__ ln_b,
            const float* __restrict__ w1, const float* __restrict__ b1,
            const float* __restrict__ w2, const float* __restrict__ b2,
            const float* __restrict__ out_w, const float* __restrict__ out_b,
            const float* __restrict__ r_a, const float* __restrict__ r_o,
            const int* __restrict__ la, const int* __restrict__ ra,
            const int* __restrict__ lo, const int* __restrict__ ro,
            float* aabP, float* babP, float* aobP, float* bobP,
            float* act, float* ptrace, float* obuf, float* upart,
            float* predbuf, float* out, float* out_sync, unsigned* bar)
{
    __shared__ LDSU ls;
    const int bid = blockIdx.x;
    const int t = threadIdx.x;
    const int b = (bid & 255) >> 3, h = bid & 7;

    for (int tick = 0; tick <= TT; ++tick) {
        // ===== P1: A (bid<256): sync_a+qh+attn, zero upart | B: sync_o(t-1)+pred(t-1) =====
        if (bid < 256 && tick < TT) {
            const float* actb = act + b * DD;
            {   // action sync, private state, one batched coherent gather
                float al0, ar0, al1, ar1;
                cload_f1x4(actb + la[t], actb + ra[t], actb + la[t + 256], actb + ra[t + 256],
                           al0, ar0, al1, ar1);
                float* AA = aabP + bid * 512; float* BA = babP + bid * 512;
                float aa0 = r_a[t] * AA[t] + al0 * ar0;            AA[t] = aa0;
                float bb0 = r_a[t] * BA[t] + 1.f;                  BA[t] = bb0;
                ls.a.syncA[t] = aa0 / sqrtf(bb0);
                float aa1 = r_a[t + 256] * AA[t + 256] + al1 * ar1; AA[t + 256] = aa1;
                float bb1 = r_a[t + 256] * BA[t + 256] + 1.f;       BA[t + 256] = bb1;
                ls.a.syncA[t + 256] = aa1 / sqrtf(bb1);
            }
            __syncthreads();
            {   // qh for head h
                int cl = t & 63, kq = t >> 6;
                const float* wp = Wqq + (size_t)(kq * 128) * 512 + h * 64 + cl;
                const float* sp = ls.a.syncA + kq * 128;
                float part = 0.f;
                #pragma unroll 8
                for (int k = 0; k < 128; ++k) part += sp[k] * wp[(size_t)k * 512];
                ls.a.red[t] = part;
            }
            __syncthreads();
            if (t < 64)
                ls.a.qs[t] = ls.a.red[t] + ls.a.red[t + 64] + ls.a.red[t + 128] + ls.a.red[t + 192]
                           + bqq[h * 64 + t];
            __syncthreads();
            {   // attention for (b,h)
                const float* kb = khT + (size_t)bid * 64 * 256;   // [dh][s]
                float sc = 0.f;
                #pragma unroll 8
                for (int dh = 0; dh < 64; ++dh) sc += ls.a.qs[dh] * kb[dh * 256 + t];
                sc *= 0.125f;
                ls.a.red[t] = sc; __syncthreads();
                for (int off = 128; off; off >>= 1) { if (t < off) ls.a.red[t] = fmaxf(ls.a.red[t], ls.a.red[t + off]); __syncthreads(); }
                float mx = ls.a.red[0]; __syncthreads();
                float e = expf(sc - mx);
                ls.a.red[t] = e; __syncthreads();
                for (int off = 128; off; off >>= 1) { if (t < off) ls.a.red[t] += ls.a.red[t + off]; __syncthreads(); }
                float inv = 1.f / ls.a.red[0];
                ls.a.ps[t] = e * inv;
                __syncthreads();
                int dh = t & 63, ch = t >> 6;
                const float* vb = vh + (size_t)bid * 256 * 64;    // [s][dh]
                float acc2 = 0.f;
                for (int s2 = ch * 64; s2 < ch * 64 + 64; ++s2) acc2 += ls.a.ps[s2] * vb[s2 * 64 + dh];
                ls.a.red[t] = acc2; __syncthreads();
                if (t < 128) ls.a.red[t] += ls.a.red[t + 128];
                __syncthreads();
                if (t < 64) astore(&obuf[b * 512 + h * 64 + t], ls.a.red[t] + ls.a.red[t + 64]);
            }
            astore2(&upart[bid * 512 + 2 * t], 0.f, 0.f);   // zero accumulator for P2
        }
        if (bid >= 256 && tick > 0) {   // B: sync_o(s) + pred(s), s = tick-1; ctile = h
            const int s = tick - 1;
            const float* actb = act + b * DD;
            float al0, ar0, al1, ar1;
            cload_f1x4(actb + lo[t], actb + ro[t], actb + lo[t + 256], actb + ro[t + 256],
                       al0, ar0, al1, ar1);
            float* AO = aobP + (bid & 255) * 512; float* BO = bobP + (bid & 255) * 512;
            float aa0 = r_o[t] * AO[t] + al0 * ar0;            AO[t] = aa0;
            float bb0 = r_o[t] * BO[t] + 1.f;                  BO[t] = bb0;
            float sv0 = aa0 / sqrtf(bb0);
            ls.b.so[t] = sv0;
            float aa1 = r_o[t + 256] * AO[t + 256] + al1 * ar1; AO[t + 256] = aa1;
            float bb1 = r_o[t + 256] * BO[t + 256] + 1.f;       BO[t + 256] = bb1;
            float sv1 = aa1 / sqrtf(bb1);
            ls.b.so[t + 256] = sv1;
            if (s == TT - 1 && h == 0) {
                out_sync[b * 512 + t] = sv0;
                out_sync[b * 512 + t + 256] = sv1;
            }
            __syncthreads();
            {   // pred: 125 cols for (b, ctile=h), K halves of 256
                int cl = t & 127, kh2 = t >> 7;
                float part = 0.f;
                if (cl < 125) {
                    int c = h * 125 + cl;
                    const float* wp = out_w + (size_t)(kh2 * 256) * 1000 + c;
                    const float* sp = ls.b.so + kh2 * 256;
                    #pragma unroll 8
                    for (int k = 0; k < 256; ++k) part += sp[k] * wp[(size_t)k * 1000];
                }
                ls.b.red[t] = part;
            }
            __syncthreads();
            if (t < 125) {
                int c = h * 125 + t;
                float v = ls.b.red[t] + ls.b.red[t + 128] + out_b[c];
                astore(&predbuf[b * 1000 + c], v);
                out[(size_t)b * NOUT * TT + (size_t)c * TT + s] = v;
            }
        }
        gbar(bar);

        // ===== P2: syn GEMM, 512 units (64 ntile x 8 ksplit), atomic-add partials =====
        if (tick < TT) {
            const int nt0 = (bid & 63) * 64;
            const int k0 = (bid >> 6) * 320;
            // batched coherent staging of A (obuf||act), 10 float4/thread, 3 waits
            vfloat4 stg[10]; const float* sp[10];
            #pragma unroll
            for (int j = 0; j < 10; ++j) {
                int idx = t + j * 256;
                int r = idx / 80, c4 = idx % 80;
                int g = k0 + c4 * 4;
                sp[j] = (g < 512) ? (obuf + r * 512 + g) : (act + r * 2048 + (g - 512));
            }
            cload_f4x4(sp[0], sp[1], sp[2], sp[3], stg[0], stg[1], stg[2], stg[3]);
            cload_f4x4(sp[4], sp[5], sp[6], sp[7], stg[4], stg[5], stg[6], stg[7]);
            cload_f4x2(sp[8], sp[9], stg[8], stg[9]);
            #pragma unroll
            for (int j = 0; j < 10; ++j) {
                int idx = t + j * 256;
                int r = idx / 80, c4 = idx % 80;
                #pragma unroll
                for (int cc = 0; cc < 4; ++cc)
                    ls.s.As[(c4 * 4 + cc) * 35 + r] = stg[j][cc];
            }
            __syncthreads();
            const int ct = t & 15, rt = t >> 4;
            const int c0 = nt0 + ct * 4, r0 = rt * 2;
            float acc0[4] = {}, acc1[4] = {};
            // split k-range so each sub-loop has a uniform weight base pointer
            const int split = (k0 < 512) ? (512 - k0 < 320 ? 512 - k0 : 320) : 0;
            {
                const float* wbase = W2 + (size_t)k0 * 4096 + c0;
                #pragma unroll 8
                for (int k = 0; k < split; ++k) {
                    vfloat4 w4 = *(const vfloat4*)(wbase + (size_t)k * 4096);
                    float a0 = ls.s.As[k * 35 + r0];
                    float a1 = ls.s.As[k * 35 + r0 + 1];
                    #pragma unroll
                    for (int j = 0; j < 4; ++j) { acc0[j] += a0 * w4[j]; acc1[j] += a1 * w4[j]; }
                }
            }
            {
                const float* wbase = syn_w + (size_t)k0 * 4096 + c0;
                #pragma unroll 8
                for (int k = split; k < 320; ++k) {
                    vfloat4 w4 = *(const vfloat4*)(wbase + (size_t)k * 4096);
                    float a0 = ls.s.As[k * 35 + r0];
                    float a1 = ls.s.As[k * 35 + r0 + 1];
                    #pragma unroll
                    for (int j = 0; j < 4; ++j) { acc0[j] += a0 * w4[j]; acc1[j] += a1 * w4[j]; }
                }
            }
            #pragma unroll
            for (int j = 0; j < 4; ++j) {
                aadd(&upart[(size_t)r0 * 4096 + c0 + j], acc0[j]);
                aadd(&upart[(size_t)(r0 + 1) * 4096 + c0 + j], acc1[j]);
            }
            __syncthreads();
        }
        gbar(bar);

        // ===== P34: fused GLU+LN+NLM (bid<256, block=(b,slice)) | cert on bid 256..287 =====
        if (tick < TT && bid < 256) {
            const int slice = h;                 // bid & 7
            const float* ub = upart + b * 4096;
            vfloat4 u0, u1, u2, u3;
            cload_f4x4(ub + 4 * t, ub + 4 * t + 1024, ub + 4 * t + 2048, ub + 4 * t + 3072,
                       u0, u1, u2, u3);
            float g0[4], g1[4]; float loc = 0.f;
            #pragma unroll
            for (int c = 0; c < 4; ++c) {
                int d0 = 4 * t + c, d1 = 1024 + 4 * t + c;
                float a0 = u0[c] + bias2[d0], bb0 = u2[c] + bias2[d0 + 2048];
                float a1 = u1[c] + bias2[d1], bb1 = u3[c] + bias2[d1 + 2048];
                g0[c] = a0 * (1.f / (1.f + expf(-bb0)));
                g1[c] = a1 * (1.f / (1.f + expf(-bb1)));
                loc += g0[c] + g1[c];
            }
            ls.g.red[t] = loc; __syncthreads();
            for (int off = 128; off; off >>= 1) { if (t < off) ls.g.red[t] += ls.g.red[t + off]; __syncthreads(); }
            float mu = ls.g.red[0] * (1.f / 2048.f); __syncthreads();
            float l2 = 0.f;
            #pragma unroll
            for (int c = 0; c < 4; ++c) {
                float dq0 = g0[c] - mu, dq1 = g1[c] - mu;
                l2 += dq0 * dq0 + dq1 * dq1;
            }
            ls.g.red[t] = l2; __syncthreads();
            for (int off = 128; off; off >>= 1) { if (t < off) ls.g.red[t] += ls.g.red[t + off]; __syncthreads(); }
            float rstd = 1.f / sqrtf(ls.g.red[0] * (1.f / 2048.f) + 1e-5f);
            __syncthreads();
            #pragma unroll
            for (int c = 0; c < 4; ++c) {
                int d0 = 4 * t + c, d1 = 1024 + 4 * t + c;
                ls.g.st[d0] = (g0[c] - mu) * rstd * ln_g[d0] + ln_b[d0];
                ls.g.st[d1] = (g1[c] - mu) * rstd * ln_g[d1] + ln_b[d1];
            }
            __syncthreads();
            // NLM for neuron d = slice*256 + t; trace is BLOCK-PRIVATE (normal cached)
            const int d = slice * 256 + t;
            float sv = ls.g.st[d];
            float* ptr = ptrace + (size_t)bid * (MM * 256);
            ptr[(tick % MM) * 256 + t] = sv;
            float hp[32];
            #pragma unroll
            for (int hh = 0; hh < 32; hh++) hp[hh] = b1[d * 32 + hh];
            for (int m = 0; m < MM; m++) {
                int mph = (tick + 1 + m) % MM;
                float tv = ptr[mph * 256 + t];
                #pragma unroll
                for (int hh = 0; hh < 32; hh++) hp[hh] += tv * w1[((size_t)m * 32 + hh) * DD + d];
            }
            float o0 = b2[d * 2], o1 = b2[d * 2 + 1];
            #pragma unroll
            for (int hh = 0; hh < 16; hh++) {
                float hv = hp[hh] * (1.f / (1.f + expf(-hp[hh + 16])));
                o0 += hv * w2[((size_t)hh * 2) * DD + d];
                o1 += hv * w2[((size_t)hh * 2 + 1) * DD + d];
            }
            astore(&act[b * DD + d], o0 * (1.f / (1.f + expf(-o1))));
        }
        if (tick > 0 && bid >= 256 && bid < 288) {   // cert(s), s = tick-1
            const int s = tick - 1;
            const int b2 = bid - 256;
            const float* pb_ = predbuf + b2 * 1000;
            float v0, v1, v2, v3;
            const float* p3 = (t < 232) ? (pb_ + t + 768) : pb_;
            cload_f1x4(pb_ + t, pb_ + t + 256, pb_ + t + 512, p3, v0, v1, v2, v3);
            float pv[4] = { v0, v1, v2, (t < 232) ? v3 : -1e30f };
            float mx = fmaxf(fmaxf(pv[0], pv[1]), fmaxf(pv[2], pv[3]));
            ls.g.red[t] = mx; __syncthreads();
            for (int off = 128; off; off >>= 1) { if (t < off) ls.g.red[t] = fmaxf(ls.g.red[t], ls.g.red[t + off]); __syncthreads(); }
            mx = ls.g.red[0]; __syncthreads();
            float s1 = 0.f, s2 = 0.f;
            #pragma unroll
            for (int ii = 0; ii < 4; ++ii) {
                int c = t + ii * 256;
                if (c < 1000) { float xx = pv[ii] - mx; float e = expf(xx); s1 += e; s2 += e * xx; }
            }
            ls.g.red[t] = s1; __syncthreads();
            for (int off = 128; off; off >>= 1) { if (t < off) ls.g.red[t] += ls.g.red[t + off]; __syncthreads(); }
            s1 = ls.g.red[0]; __syncthreads();
            ls.g.red[t] = s2; __syncthreads();
            for (int off = 128; off; off >>= 1) { if (t < off) ls.g.red[t] += ls.g.red[t + off]; __syncthreads(); }
            s2 = ls.g.red[0];
            if (t == 0) {
                float ne = -(s2 / s1 - logf(s1)) * (1.f / logf(1000.f));
                size_t base = (size_t)BB * NOUT * TT + (size_t)b2 * 2 * TT + s;
                out[base] = ne;
                out[base + TT] = 1.f - ne;
            }
        }
        gbar(bar);
    }
}

// ---------------------------------------------------------------------------
extern "C" void kernel_launch(void* const* d_in, const int* in_sizes, int n_in,
                              void* d_out, int out_size, void* d_ws, size_t ws_size,
                              hipStream_t stream)
{
    const float* x        = (const float*)d_in[0];
    const float* kv_w     = (const float*)d_in[1];
    const float* kv_b     = (const float*)d_in[2];
    const float* ln_kv_g  = (const float*)d_in[3];
    const float* ln_kv_b  = (const float*)d_in[4];
    const float* q_w      = (const float*)d_in[5];
    const float* q_b      = (const float*)d_in[6];
    const float* Wq       = (const float*)d_in[7];
    const float* bq       = (const float*)d_in[8];
    const float* Wk       = (const float*)d_in[9];
    const float* bk       = (const float*)d_in[10];
    const float* Wv       = (const float*)d_in[11];
    const float* bv       = (const float*)d_in[12];
    const float* Wo       = (const float*)d_in[13];
    const float* bo       = (const float*)d_in[14];
    const float* syn_w    = (const float*)d_in[15];
    const float* syn_b    = (const float*)d_in[16];
    const float* ln_syn_g = (const float*)d_in[17];
    const float* ln_syn_b = (const float*)d_in[18];
    const float* nlm_w1   = (const float*)d_in[19];
    const float* nlm_b1   = (const float*)d_in[20];
    const float* nlm_w2   = (const float*)d_in[21];
    const float* nlm_b2   = (const float*)d_in[22];
    const float* out_w    = (const float*)d_in[23];
    const float* out_b    = (const float*)d_in[24];
    const float* dec_a    = (const float*)d_in[25];
    const float* dec_o    = (const float*)d_in[26];
    const float* start_tr = (const float*)d_in[27];
    const float* start_ac = (const float*)d_in[28];
    const int*   idx_la   = (const int*)d_in[29];
    const int*   idx_ra   = (const int*)d_in[30];
    const int*   idx_lo   = (const int*)d_in[31];
    const int*   idx_ro   = (const int*)d_in[32];
    float* out = (float*)d_out;

    // workspace carve (floats)
    float* w = (float*)d_ws;
    float* kvbuf  = w;            w += (size_t)8192 * 512;
    float* khT    = w;            w += (size_t)8192 * 512;
    float* vhb    = w;            w += (size_t)8192 * 512;
    float* Wqq    = w;            w += (size_t)512 * 512;
    float* bqq    = w;            w += 512;
    float* W2     = w;            w += (size_t)512 * 4096;
    float* bias2  = w;            w += 4096;
    float* r_a    = w;            w += 512;
    float* r_o    = w;            w += 512;
    float* aabP   = w;            w += (size_t)256 * 512;
    float* babP   = w;            w += (size_t)256 * 512;
    float* aobP   = w;            w += (size_t)256 * 512;
    float* bobP   = w;            w += (size_t)256 * 512;
    float* act    = w;            w += BB * DD;
    float* ptrace = w;            w += (size_t)256 * MM * 256;
    float* obuf   = w;            w += BB * DIN;
    float* upart  = w;            w += (size_t)32 * 4096;
    float* predbuf= w;            w += BB * NOUT;
    unsigned* bar = (unsigned*)w; w += 4096;

    // ---- precompute ----
    init_kernel<<<6400, 256, 0, stream>>>(dec_a, dec_o, start_ac, start_tr, idx_lo, idx_ro,
                                          r_a, r_o, aabP, babP, aobP, bobP, act, ptrace,
                                          upart, bar);
    gemm64<1, 0><<<dim3(128, 8), 256, 0, stream>>>(x, kv_w, kv_b, kvbuf, 8192, 512, 512);
    ln_rows<<<8192, 256, 0, stream>>>(kvbuf, ln_kv_g, ln_kv_b);
    gemm64<0, 1><<<dim3(128, 8), 256, 0, stream>>>(kvbuf, Wk, bk, khT, 8192, 512, 512);
    gemm64<0, 2><<<dim3(128, 8), 256, 0, stream>>>(kvbuf, Wv, bv, vhb, 8192, 512, 512);
    gemm64<0, 0><<<dim3(8, 8), 256, 0, stream>>>(q_w, Wq, nullptr, Wqq, 512, 512, 512);
    bqq_kernel<<<2, 256, 0, stream>>>(q_b, Wq, bq, bqq);
    gemm64<0, 0><<<dim3(8, 64), 256, 0, stream>>>(Wo, syn_w, nullptr, W2, 512, 4096, 512);
    bias2_kernel<<<16, 256, 0, stream>>>(bo, syn_w, syn_b, bias2);

    float* out_sync = out + (size_t)BB * NOUT * TT + (size_t)BB * 2 * TT;

    // ---- persistent 50-tick loop ----
    mega_kernel<<<NBLK, 256, 0, stream>>>(Wqq, bqq, khT, vhb, W2, syn_w, bias2,
                                          ln_syn_g, ln_syn_b,
                                          nlm_w1, nlm_b1, nlm_w2, nlm_b2,
                                          out_w, out_b, r_a, r_o,
                                          idx_la, idx_ra, idx_lo, idx_ro,
                                          aabP, babP, aobP, bobP,
                                          act, ptrace, obuf, upart,
                                          predbuf, out, out_sync, bar);
}

// Round 6
// 8821.907 us; speedup vs baseline: 4.2956x; 1.8091x over previous
//
#include <hip/hip_runtime.h>
#include <math.h>

// Problem constants
#define BB 32
#define CC 512
#define SS 256
#define DD 2048
#define DIN 512
#define NH 8
#define DHD 64
#define TT 50
#define MM 25
#define NSA 512
#define NSO 512
#define NOUT 1000

typedef float vfloat4 __attribute__((ext_vector_type(4)));

// ---------------------------------------------------------------------------
// Init: decays, parity action-sync state, single-owner out-sync state,
// act0, trace0
// ---------------------------------------------------------------------------
__global__ void init_kernel(const float* __restrict__ dec_a, const float* __restrict__ dec_o,
                            const float* __restrict__ start_act, const float* __restrict__ start_trace,
                            const int* __restrict__ idx_lo, const int* __restrict__ idx_ro,
                            float* __restrict__ r_a, float* __restrict__ r_o,
                            float* __restrict__ aab, float* __restrict__ bab,
                            float* __restrict__ aob, float* __restrict__ bob,
                            float* __restrict__ act, float* __restrict__ trace)
{
    int i = blockIdx.x * 256 + threadIdx.x;
    if (i < 512) {
        r_a[i] = expf(-fminf(fmaxf(dec_a[i], 0.f), 15.f));
        r_o[i] = expf(-fminf(fmaxf(dec_o[i], 0.f), 15.f));
    }
    if (i < 2 * 16384) { aab[i] = 0.f; bab[i] = 0.f; }
    if (i < 16384) {
        int j = i & 511;
        aob[i] = start_act[idx_lo[j]] * start_act[idx_ro[j]];
        bob[i] = 1.f;
    }
    if (i < BB * DD) act[i] = start_act[i & (DD - 1)];
    if (i < BB * MM * DD) {
        int rem = i % (MM * DD);
        int m = rem / DD, d = rem % DD;
        trace[i] = start_trace[d * MM + m];   // trace layout [b][m][d]
    }
}

// ---------------------------------------------------------------------------
// Precompute GEMMs (verbatim, validated round 1)
// ---------------------------------------------------------------------------
template<int AMODE, int SMODE>
__global__ void gemm64(const float* __restrict__ A, const float* __restrict__ Bm,
                       const float* __restrict__ bias, float* __restrict__ Cm,
                       int Mdim, int Ndim, int Kdim)
{
    __shared__ float As[16 * 65];
    __shared__ float Bs[16 * 64];
    int row0 = blockIdx.x * 64;
    int col0 = blockIdx.y * 64;
    int t = threadIdx.x;
    int tx = t & 15, ty = t >> 4;
    float acc[4][4] = {};
    for (int k0 = 0; k0 < Kdim; k0 += 16) {
        if (AMODE == 0) {
            for (int i = t; i < 1024; i += 256) {
                int kk = i & 15, r = i >> 4;
                As[kk * 65 + r] = A[(size_t)(row0 + r) * Kdim + k0 + kk];
            }
        } else {
            int b = row0 / SS, s0 = row0 % SS;
            for (int i = t; i < 1024; i += 256) {
                int r = i & 63, kk = i >> 6;
                As[kk * 65 + r] = A[((size_t)b * CC + k0 + kk) * SS + s0 + r];
            }
        }
        for (int i = t; i < 1024; i += 256) {
            int c = i & 63, kk = i >> 6;
            Bs[kk * 64 + c] = Bm[(size_t)(k0 + kk) * Ndim + col0 + c];
        }
        __syncthreads();
        #pragma unroll
        for (int kk = 0; kk < 16; ++kk) {
            float a[4], bb[4];
            #pragma unroll
            for (int i = 0; i < 4; i++) a[i] = As[kk * 65 + ty * 4 + i];
            #pragma unroll
            for (int j = 0; j < 4; j++) bb[j] = Bs[kk * 64 + tx * 4 + j];
            #pragma unroll
            for (int i = 0; i < 4; i++)
                #pragma unroll
                for (int j = 0; j < 4; j++) acc[i][j] += a[i] * bb[j];
        }
        __syncthreads();
    }
    #pragma unroll
    for (int i = 0; i < 4; i++)
        #pragma unroll
        for (int j = 0; j < 4; j++) {
            int row = row0 + ty * 4 + i, col = col0 + tx * 4 + j;
            float v = acc[i][j] + (bias ? bias[col] : 0.f);
            if (SMODE == 0) {
                Cm[(size_t)row * Ndim + col] = v;
            } else if (SMODE == 1) {
                int b = row / SS, s = row % SS, h = col >> 6, dh = col & 63;
                Cm[(((size_t)b * NH + h) * DHD + dh) * SS + s] = v;
            } else {
                int b = row / SS, s = row % SS, h = col >> 6, dh = col & 63;
                Cm[(((size_t)b * NH + h) * SS + s) * DHD + dh] = v;
            }
        }
}

__global__ void ln_rows(float* __restrict__ buf, const float* __restrict__ g,
                        const float* __restrict__ bta)
{
    int row = blockIdx.x, t = threadIdx.x;
    __shared__ float red[256];
    float v0 = buf[(size_t)row * 512 + t];
    float v1 = buf[(size_t)row * 512 + 256 + t];
    red[t] = v0 + v1; __syncthreads();
    for (int off = 128; off; off >>= 1) { if (t < off) red[t] += red[t + off]; __syncthreads(); }
    float mu = red[0] * (1.f / 512.f); __syncthreads();
    float d0 = v0 - mu, d1 = v1 - mu;
    red[t] = d0 * d0 + d1 * d1; __syncthreads();
    for (int off = 128; off; off >>= 1) { if (t < off) red[t] += red[t + off]; __syncthreads(); }
    float rstd = 1.f / sqrtf(red[0] * (1.f / 512.f) + 1e-5f);
    buf[(size_t)row * 512 + t]       = d0 * rstd * g[t] + bta[t];
    buf[(size_t)row * 512 + 256 + t] = d1 * rstd * g[t + 256] + bta[t + 256];
}

__global__ void bqq_kernel(const float* __restrict__ q_b, const float* __restrict__ Wq,
                           const float* __restrict__ bq, float* __restrict__ bqq)
{
    int c = blockIdx.x * 256 + threadIdx.x;
    if (c >= 512) return;
    float acc = bq[c];
    for (int k = 0; k < 512; k++) acc += q_b[k] * Wq[k * 512 + c];
    bqq[c] = acc;
}

__global__ void bias2_kernel(const float* __restrict__ bo, const float* __restrict__ syn_w,
                             const float* __restrict__ syn_b, float* __restrict__ bias2)
{
    int c = blockIdx.x * 256 + threadIdx.x;
    if (c >= 4096) return;
    float acc = syn_b[c];
    for (int k = 0; k < 512; k++) acc += bo[k] * syn_w[(size_t)k * 4096 + c];
    bias2[c] = acc;
}

// ---------------------------------------------------------------------------
// k_front: blocks 0..255  = tick-t action path  (sync_a + qh + attn -> obuf)
//          blocks 256..287 = tick-(t-1) output path (sync_o + pred + cert)
// Cross-kernel coherence via dispatch boundaries; all loads/stores normal.
// ---------------------------------------------------------------------------
__global__ void __launch_bounds__(256)
k_front(const float* __restrict__ act, const int* __restrict__ la, const int* __restrict__ ra,
        const float* __restrict__ r_a, float* __restrict__ aab, float* __restrict__ bab,
        const float* __restrict__ Wqq, const float* __restrict__ bqq,
        const float* __restrict__ khT, const float* __restrict__ vh, float* __restrict__ obuf,
        const int* __restrict__ lo, const int* __restrict__ ro, const float* __restrict__ r_o,
        float* __restrict__ aob, float* __restrict__ bob,
        const float* __restrict__ out_w, const float* __restrict__ out_b,
        float* __restrict__ out, float* __restrict__ out_sync, int tick)
{
    const int bid = blockIdx.x;
    const int t = threadIdx.x;
    if (bid < 256) {
        if (tick >= TT) return;
        const int b = bid >> 3, h = bid & 7;
        __shared__ float syncA[512];
        __shared__ float qs[64];
        __shared__ float red[256];
        __shared__ float ps[256];
        const float* actb = act + b * DD;
        {   // action sync: parity state, h==0 writes next parity
            const int rd = tick & 1, wr = 1 - rd;
            const float* AAr = aab + rd * 16384 + b * 512;
            float*       AAw = aab + wr * 16384 + b * 512;
            const float* BAr = bab + rd * 16384 + b * 512;
            float*       BAw = bab + wr * 16384 + b * 512;
            #pragma unroll
            for (int jj = 0; jj < 2; ++jj) {
                int j = t + jj * 256;
                float p = actb[la[j]] * actb[ra[j]];
                float aa = r_a[j] * AAr[j] + p;
                float bb = r_a[j] * BAr[j] + 1.f;
                if (h == 0) { AAw[j] = aa; BAw[j] = bb; }
                syncA[j] = aa / sqrtf(bb);
            }
        }
        __syncthreads();
        {   // qh for head h: 64 cols, k split over 4 thread groups
            int cl = t & 63, kq = t >> 6;
            const float* wp = Wqq + (size_t)(kq * 128) * 512 + h * 64 + cl;
            const float* sp = syncA + kq * 128;
            float part = 0.f;
            #pragma unroll 8
            for (int k = 0; k < 128; ++k) part += sp[k] * wp[(size_t)k * 512];
            red[t] = part;
        }
        __syncthreads();
        if (t < 64)
            qs[t] = red[t] + red[t + 64] + red[t + 128] + red[t + 192] + bqq[h * 64 + t];
        __syncthreads();
        {   // attention for (b,h)
            const float* kb = khT + (size_t)bid * 64 * 256;   // [dh][s]
            float sc = 0.f;
            #pragma unroll 8
            for (int dh = 0; dh < 64; ++dh) sc += qs[dh] * kb[dh * 256 + t];
            sc *= 0.125f;
            red[t] = sc; __syncthreads();
            for (int off = 128; off; off >>= 1) { if (t < off) red[t] = fmaxf(red[t], red[t + off]); __syncthreads(); }
            float mx = red[0]; __syncthreads();
            float e = expf(sc - mx);
            red[t] = e; __syncthreads();
            for (int off = 128; off; off >>= 1) { if (t < off) red[t] += red[t + off]; __syncthreads(); }
            float inv = 1.f / red[0];
            ps[t] = e * inv;
            __syncthreads();
            int dh = t & 63, ch = t >> 6;
            const float* vb = vh + (size_t)bid * 256 * 64;    // [s][dh]
            float acc2 = 0.f;
            for (int s2 = ch * 64; s2 < ch * 64 + 64; ++s2) acc2 += ps[s2] * vb[s2 * 64 + dh];
            red[t] = acc2; __syncthreads();
            if (t < 128) red[t] += red[t + 128];
            __syncthreads();
            if (t < 64) obuf[b * 512 + h * 64 + t] = red[t] + red[t + 64];
        }
    } else {
        if (tick == 0) return;
        const int s = tick - 1;
        const int b = bid - 256;
        __shared__ float so[512];
        __shared__ float ps2[1024];
        __shared__ float red2[256];
        const float* actb = act + b * DD;
        float* AO = aob + b * 512; float* BO = bob + b * 512;   // single owner
        #pragma unroll
        for (int jj = 0; jj < 2; ++jj) {
            int j = t + jj * 256;
            float p = actb[lo[j]] * actb[ro[j]];
            float aa = r_o[j] * AO[j] + p; AO[j] = aa;
            float bb = r_o[j] * BO[j] + 1.f; BO[j] = bb;
            float sv = aa / sqrtf(bb);
            so[j] = sv;
            if (s == TT - 1) out_sync[b * 512 + j] = sv;
        }
        __syncthreads();
        // pred: 8 groups of 125 cols, K in halves of 256 (kh2 = t>>7)
        const int cl = t & 127, kh2 = t >> 7;
        for (int cc = 0; cc < 8; ++cc) {
            float part = 0.f;
            if (cl < 125) {
                int c = cc * 125 + cl;
                const float* wp = out_w + (size_t)(kh2 * 256) * 1000 + c;
                const float* sp = so + kh2 * 256;
                #pragma unroll 8
                for (int k = 0; k < 256; ++k) part += sp[k] * wp[(size_t)k * 1000];
            }
            red2[t] = part;
            __syncthreads();
            if (t < 125) {
                int c2 = cc * 125 + t;
                float v = red2[t] + red2[t + 128] + out_b[c2];
                ps2[c2] = v;
                out[(size_t)b * NOUT * TT + (size_t)c2 * TT + s] = v;
            }
            __syncthreads();
        }
        // cert from LDS preds
        float pv[4];
        float mx = -1e30f;
        #pragma unroll
        for (int ii = 0; ii < 4; ++ii) {
            int c = t + ii * 256;
            float v = (c < 1000) ? ps2[c] : -1e30f;
            pv[ii] = v;
            mx = fmaxf(mx, v);
        }
        red2[t] = mx; __syncthreads();
        for (int off = 128; off; off >>= 1) { if (t < off) red2[t] = fmaxf(red2[t], red2[t + off]); __syncthreads(); }
        mx = red2[0]; __syncthreads();
        float s1 = 0.f, s2 = 0.f;
        #pragma unroll
        for (int ii = 0; ii < 4; ++ii) {
            int c = t + ii * 256;
            if (c < 1000) { float xx = pv[ii] - mx; float e = expf(xx); s1 += e; s2 += e * xx; }
        }
        red2[t] = s1; __syncthreads();
        for (int off = 128; off; off >>= 1) { if (t < off) red2[t] += red2[t + off]; __syncthreads(); }
        s1 = red2[0]; __syncthreads();
        red2[t] = s2; __syncthreads();
        for (int off = 128; off; off >>= 1) { if (t < off) red2[t] += red2[t + off]; __syncthreads(); }
        s2 = red2[0];
        if (t == 0) {
            float ne = -(s2 / s1 - logf(s1)) * (1.f / logf(1000.f));
            size_t base = (size_t)BB * NOUT * TT + (size_t)b * 2 * TT + s;
            out[base] = ne;
            out[base + TT] = 1.f - ne;
        }
    }
}

// ---------------------------------------------------------------------------
// k_syn: u = [obuf | act] @ [W2 ; syn_w[512:]] partials.
// 512 blocks = 64 n-tiles (64 cols) x 8 k-splits (320 rows). Plain stores.
// ---------------------------------------------------------------------------
__global__ void __launch_bounds__(256)
k_syn(const float* __restrict__ obuf, const float* __restrict__ act,
      const float* __restrict__ W2, const float* __restrict__ syn_w,
      float* __restrict__ upart)
{
    __shared__ float As[320 * 35];
    const int nt0 = (blockIdx.x & 63) * 64;
    const int k0 = (blockIdx.x >> 6) * 320;
    const int t = threadIdx.x;
    for (int i = t; i < 32 * 80; i += 256) {
        int r = i / 80, c4 = i % 80;
        int g = k0 + c4 * 4;
        const float* p = (g < 512) ? (obuf + r * 512 + g) : (act + r * 2048 + (g - 512));
        vfloat4 v = *(const vfloat4*)p;
        #pragma unroll
        for (int cc = 0; cc < 4; ++cc)
            As[(c4 * 4 + cc) * 35 + r] = v[cc];
    }
    __syncthreads();
    const int ct = t & 15, rt = t >> 4;
    const int c0 = nt0 + ct * 4, r0 = rt * 2;
    float acc0[4] = {}, acc1[4] = {};
    const int split = (k0 < 512) ? (512 - k0 < 320 ? 512 - k0 : 320) : 0;
    {
        const float* wbase = W2 + (size_t)k0 * 4096 + c0;
        #pragma unroll 8
        for (int k = 0; k < split; ++k) {
            vfloat4 w4 = *(const vfloat4*)(wbase + (size_t)k * 4096);
            float a0 = As[k * 35 + r0];
            float a1 = As[k * 35 + r0 + 1];
            #pragma unroll
            for (int j = 0; j < 4; ++j) { acc0[j] += a0 * w4[j]; acc1[j] += a1 * w4[j]; }
        }
    }
    {
        const float* wbase = syn_w + (size_t)k0 * 4096 + c0;
        #pragma unroll 8
        for (int k = split; k < 320; ++k) {
            vfloat4 w4 = *(const vfloat4*)(wbase + (size_t)k * 4096);
            float a0 = As[k * 35 + r0];
            float a1 = As[k * 35 + r0 + 1];
            #pragma unroll
            for (int j = 0; j < 4; ++j) { acc0[j] += a0 * w4[j]; acc1[j] += a1 * w4[j]; }
        }
    }
    const int ks = blockIdx.x >> 6;
    *(vfloat4*)(upart + ((size_t)(ks * 32) + r0) * 4096 + c0)     = *(vfloat4*)acc0;
    *(vfloat4*)(upart + ((size_t)(ks * 32) + r0 + 1) * 4096 + c0) = *(vfloat4*)acc1;
}

// ---------------------------------------------------------------------------
// k_p34: fused partial-sum + bias + GLU + LayerNorm + NLM. 256 blocks =
// (b, slice). LN stats computed redundantly per sibling (bitwise identical).
// ---------------------------------------------------------------------------
__global__ void __launch_bounds__(256)
k_p34(const float* __restrict__ upart, const float* __restrict__ bias2,
      const float* __restrict__ ln_g, const float* __restrict__ ln_b,
      const float* __restrict__ w1, const float* __restrict__ b1,
      const float* __restrict__ w2, const float* __restrict__ b2,
      float* __restrict__ trace, float* __restrict__ act, int tick)
{
    __shared__ float st[2048];
    __shared__ float red[256];
    const int bid = blockIdx.x, t = threadIdx.x;
    const int b = bid >> 3, slice = bid & 7;
    vfloat4 s0 = {0.f, 0.f, 0.f, 0.f}, s1 = s0, s2 = s0, s3 = s0;
    #pragma unroll
    for (int ks = 0; ks < 8; ++ks) {
        const float* ub = upart + (size_t)(ks * 32 + b) * 4096;
        s0 += *(const vfloat4*)(ub + 4 * t);
        s1 += *(const vfloat4*)(ub + 4 * t + 1024);
        s2 += *(const vfloat4*)(ub + 4 * t + 2048);
        s3 += *(const vfloat4*)(ub + 4 * t + 3072);
    }
    float g0[4], g1[4]; float loc = 0.f;
    #pragma unroll
    for (int c = 0; c < 4; ++c) {
        int d0 = 4 * t + c, d1 = 1024 + 4 * t + c;
        float a0 = s0[c] + bias2[d0], bb0 = s2[c] + bias2[d0 + 2048];
        float a1 = s1[c] + bias2[d1], bb1 = s3[c] + bias2[d1 + 2048];
        g0[c] = a0 * (1.f / (1.f + expf(-bb0)));
        g1[c] = a1 * (1.f / (1.f + expf(-bb1)));
        loc += g0[c] + g1[c];
    }
    red[t] = loc; __syncthreads();
    for (int off = 128; off; off >>= 1) { if (t < off) red[t] += red[t + off]; __syncthreads(); }
    float mu = red[0] * (1.f / 2048.f); __syncthreads();
    float l2 = 0.f;
    #pragma unroll
    for (int c = 0; c < 4; ++c) {
        float dq0 = g0[c] - mu, dq1 = g1[c] - mu;
        l2 += dq0 * dq0 + dq1 * dq1;
    }
    red[t] = l2; __syncthreads();
    for (int off = 128; off; off >>= 1) { if (t < off) red[t] += red[t + off]; __syncthreads(); }
    float rstd = 1.f / sqrtf(red[0] * (1.f / 2048.f) + 1e-5f);
    __syncthreads();
    #pragma unroll
    for (int c = 0; c < 4; ++c) {
        int d0 = 4 * t + c, d1 = 1024 + 4 * t + c;
        st[d0] = (g0[c] - mu) * rstd * ln_g[d0] + ln_b[d0];
        st[d1] = (g1[c] - mu) * rstd * ln_g[d1] + ln_b[d1];
    }
    __syncthreads();
    // NLM for neuron d = slice*256 + t; trace [b][m][d] global, plain access
    const int d = slice * 256 + t;
    float sv = st[d];
    float* ptr = trace + (size_t)b * MM * DD;
    ptr[(tick % MM) * DD + d] = sv;
    float hp[32];
    #pragma unroll
    for (int hh = 0; hh < 32; hh++) hp[hh] = b1[d * 32 + hh];
    for (int m = 0; m < MM; m++) {
        int mph = (tick + 1 + m) % MM;
        float tv = ptr[mph * DD + d];
        #pragma unroll
        for (int hh = 0; hh < 32; hh++) hp[hh] += tv * w1[((size_t)m * 32 + hh) * DD + d];
    }
    float o0 = b2[d * 2], o1 = b2[d * 2 + 1];
    #pragma unroll
    for (int hh = 0; hh < 16; hh++) {
        float hv = hp[hh] * (1.f / (1.f + expf(-hp[hh + 16])));
        o0 += hv * w2[((size_t)hh * 2) * DD + d];
        o1 += hv * w2[((size_t)hh * 2 + 1) * DD + d];
    }
    act[b * DD + d] = o0 * (1.f / (1.f + expf(-o1)));
}

// ---------------------------------------------------------------------------
extern "C" void kernel_launch(void* const* d_in, const int* in_sizes, int n_in,
                              void* d_out, int out_size, void* d_ws, size_t ws_size,
                              hipStream_t stream)
{
    const float* x        = (const float*)d_in[0];
    const float* kv_w     = (const float*)d_in[1];
    const float* kv_b     = (const float*)d_in[2];
    const float* ln_kv_g  = (const float*)d_in[3];
    const float* ln_kv_b  = (const float*)d_in[4];
    const float* q_w      = (const float*)d_in[5];
    const float* q_b      = (const float*)d_in[6];
    const float* Wq       = (const float*)d_in[7];
    const float* bq       = (const float*)d_in[8];
    const float* Wk       = (const float*)d_in[9];
    const float* bk       = (const float*)d_in[10];
    const float* Wv       = (const float*)d_in[11];
    const float* bv       = (const float*)d_in[12];
    const float* Wo       = (const float*)d_in[13];
    const float* bo       = (const float*)d_in[14];
    const float* syn_w    = (const float*)d_in[15];
    const float* syn_b    = (const float*)d_in[16];
    const float* ln_syn_g = (const float*)d_in[17];
    const float* ln_syn_b = (const float*)d_in[18];
    const float* nlm_w1   = (const float*)d_in[19];
    const float* nlm_b1   = (const float*)d_in[20];
    const float* nlm_w2   = (const float*)d_in[21];
    const float* nlm_b2   = (const float*)d_in[22];
    const float* out_w    = (const float*)d_in[23];
    const float* out_b    = (const float*)d_in[24];
    const float* dec_a    = (const float*)d_in[25];
    const float* dec_o    = (const float*)d_in[26];
    const float* start_tr = (const float*)d_in[27];
    const float* start_ac = (const float*)d_in[28];
    const int*   idx_la   = (const int*)d_in[29];
    const int*   idx_ra   = (const int*)d_in[30];
    const int*   idx_lo   = (const int*)d_in[31];
    const int*   idx_ro   = (const int*)d_in[32];
    float* out = (float*)d_out;

    // workspace carve (floats)
    float* w = (float*)d_ws;
    float* kvbuf  = w;            w += (size_t)8192 * 512;
    float* khT    = w;            w += (size_t)8192 * 512;
    float* vhb    = w;            w += (size_t)8192 * 512;
    float* Wqq    = w;            w += (size_t)512 * 512;
    float* bqq    = w;            w += 512;
    float* W2     = w;            w += (size_t)512 * 4096;
    float* bias2  = w;            w += 4096;
    float* r_a    = w;            w += 512;
    float* r_o    = w;            w += 512;
    float* aab    = w;            w += 2 * 16384;
    float* bab    = w;            w += 2 * 16384;
    float* aob    = w;            w += 16384;
    float* bob    = w;            w += 16384;
    float* act    = w;            w += BB * DD;
    float* trace  = w;            w += (size_t)BB * MM * DD;
    float* obuf   = w;            w += BB * DIN;
    float* upart  = w;            w += (size_t)8 * 32 * 4096;

    // ---- precompute ----
    init_kernel<<<6400, 256, 0, stream>>>(dec_a, dec_o, start_ac, start_tr, idx_lo, idx_ro,
                                          r_a, r_o, aab, bab, aob, bob, act, trace);
    gemm64<1, 0><<<dim3(128, 8), 256, 0, stream>>>(x, kv_w, kv_b, kvbuf, 8192, 512, 512);
    ln_rows<<<8192, 256, 0, stream>>>(kvbuf, ln_kv_g, ln_kv_b);
    gemm64<0, 1><<<dim3(128, 8), 256, 0, stream>>>(kvbuf, Wk, bk, khT, 8192, 512, 512);
    gemm64<0, 2><<<dim3(128, 8), 256, 0, stream>>>(kvbuf, Wv, bv, vhb, 8192, 512, 512);
    gemm64<0, 0><<<dim3(8, 8), 256, 0, stream>>>(q_w, Wq, nullptr, Wqq, 512, 512, 512);
    bqq_kernel<<<2, 256, 0, stream>>>(q_b, Wq, bq, bqq);
    gemm64<0, 0><<<dim3(8, 64), 256, 0, stream>>>(Wo, syn_w, nullptr, W2, 512, 4096, 512);
    bias2_kernel<<<16, 256, 0, stream>>>(bo, syn_w, syn_b, bias2);

    float* out_sync = out + (size_t)BB * NOUT * TT + (size_t)BB * 2 * TT;

    // ---- recurrent ticks: 3 dispatches/tick + final output tail ----
    for (int t = 0; t <= TT; ++t) {
        k_front<<<288, 256, 0, stream>>>(act, idx_la, idx_ra, r_a, aab, bab,
                                         Wqq, bqq, khT, vhb, obuf,
                                         idx_lo, idx_ro, r_o, aob, bob,
                                         out_w, out_b, out, out_sync, t);
        if (t < TT) {
            k_syn<<<512, 256, 0, stream>>>(obuf, act, W2, syn_w, upart);
            k_p34<<<256, 256, 0, stream>>>(upart, bias2, ln_syn_g, ln_syn_b,
                                           nlm_w1, nlm_b1, nlm_w2, nlm_b2,
                                           trace, act, t);
        }
    }
}